// Round 3
// baseline (17253.069 us; speedup 1.0000x reference)
//
#include <hip/hip_runtime.h>
#include <hip/hip_bf16.h>

#define HIDF 128
#define OUTF 64

// ---------------- degree kernels ----------------
__global__ __launch_bounds__(256) void deg_zero(float* __restrict__ d, int N) {
    int i = blockIdx.x * 256 + threadIdx.x;
    if (i < N) d[i] = 0.f;
}

__global__ __launch_bounds__(256) void deg_count(const int* __restrict__ ei, float* __restrict__ d, int E) {
    int e = blockIdx.x * 256 + threadIdx.x;
    if (e < E) atomicAdd(&d[ei[E + e]], 1.f);
}

__global__ __launch_bounds__(256) void deg_fin(float* __restrict__ d, int N) {
    int i = blockIdx.x * 256 + threadIdx.x;
    if (i < N) d[i] = rsqrtf(d[i] + 1.f);
}

// ---------------- GEMM: T[N,128] = relu?(X) @ W  (fp32; W from global/L1, X tile in LDS) ----------------
template <bool RELU_IN>
__global__ __launch_bounds__(256) void gemm128(const float* __restrict__ X,
                                               const float* __restrict__ W,
                                               float* __restrict__ T, int N) {
    __shared__ float Xs[8][HIDF];               // 4 KB
    const int tid = threadIdx.x;
    const int j4  = tid & 31;   // 4-column group
    const int sub = tid >> 5;   // 0..7 node within group
    const int ngroups = (N + 7) >> 3;
    const float4* Wrow = (const float4*)W;      // row k -> Wrow[k*32 + j4]

    for (int g = blockIdx.x; g < ngroups; g += gridDim.x) {
        const int nb = g << 3;
        __syncthreads();  // protect Xs from previous iteration's readers
        for (int i = tid; i < 8 * HIDF; i += 256) {
            int n = nb + (i >> 7);
            int k = i & 127;
            float v = 0.f;
            if (n < N) {
                v = X[(size_t)n * HIDF + k];
                if (RELU_IN) v = fmaxf(v, 0.f);
            }
            Xs[i >> 7][k] = v;
        }
        __syncthreads();
        const int n = nb + sub;
        float4 acc = make_float4(0.f, 0.f, 0.f, 0.f);
        #pragma unroll 8
        for (int k = 0; k < HIDF; ++k) {
            float x = Xs[sub][k];
            float4 w = Wrow[k * 32 + j4];
            acc.x = fmaf(x, w.x, acc.x);
            acc.y = fmaf(x, w.y, acc.y);
            acc.z = fmaf(x, w.z, acc.z);
            acc.w = fmaf(x, w.w, acc.w);
        }
        if (n < N) *((float4*)&T[(size_t)n * HIDF + j4 * 4]) = acc;
    }
}

// ---------------- O[n,:] = T[n,:]*dinv[n]^2 + b   (self-loop + bias; full init) ----------------
__global__ __launch_bounds__(256) void agg_init(const float* __restrict__ T,
                                                const float* __restrict__ dinv,
                                                const float* __restrict__ b,
                                                float* __restrict__ O, int N) {
    int g = blockIdx.x * 256 + threadIdx.x;  // float4 index
    int total = N * (HIDF / 4);
    if (g >= total) return;
    int n  = g >> 5;
    int j4 = g & 31;
    float d2 = dinv[n];
    d2 *= d2;
    float4 t = ((const float4*)T)[g];
    const float4 bv = ((const float4*)b)[j4];
    float4 o;
    o.x = fmaf(t.x, d2, bv.x);
    o.y = fmaf(t.y, d2, bv.y);
    o.z = fmaf(t.z, d2, bv.z);
    o.w = fmaf(t.w, d2, bv.w);
    ((float4*)O)[g] = o;
}

// ---------------- edge scatter: O[dst,:] += T[src,:]*dinv[src]*dinv[dst] ----------------
__global__ __launch_bounds__(256) void agg_edge(const float* __restrict__ T,
                                                const float* __restrict__ dinv,
                                                const int* __restrict__ ei,
                                                float* __restrict__ O, int E) {
    long g = (long)blockIdx.x * 256 + threadIdx.x;
    long e = g >> 5;          // 32 threads per edge
    if (e >= E) return;
    int j4  = (int)(g & 31);
    int src = ei[e];
    int dst = ei[E + e];
    float nrm = dinv[src] * dinv[dst];
    float4 t = ((const float4*)(T + (size_t)src * HIDF))[j4];
    float* o = O + (size_t)dst * HIDF + j4 * 4;
    atomicAdd(o + 0, t.x * nrm);
    atomicAdd(o + 1, t.y * nrm);
    atomicAdd(o + 2, t.z * nrm);
    atomicAdd(o + 3, t.w * nrm);
}

// ---------------- meta: scores -> softmax -> weighted sum + h1 residual -> @Wf + bf ----------------
__global__ __launch_bounds__(256) void meta_kernel(const float* __restrict__ H1,
                                                   const float* __restrict__ H2,
                                                   const float* __restrict__ H3,
                                                   const float* __restrict__ Wa,
                                                   const float* __restrict__ ba,
                                                   const float* __restrict__ Wf,
                                                   const float* __restrict__ bfb,
                                                   float* __restrict__ out, int N) {
    __shared__ float WfS[HIDF * OUTF];  // 32 KB
    __shared__ float WaS[HIDF];
    __shared__ float hm[4][HIDF];
    const int tid = threadIdx.x;
    for (int i = tid; i < HIDF * OUTF; i += 256) WfS[i] = Wf[i];
    if (tid < HIDF) WaS[tid] = Wa[tid];
    __syncthreads();
    const float bav = ba[0];
    const int w = tid >> 6;   // wave id: node within group of 4
    const int l = tid & 63;   // lane
    const float bfv = bfb[l];
    const int iters = (N + 3) >> 2;

    for (int it = blockIdx.x; it < iters; it += gridDim.x) {
        const int n = it * 4 + w;
        __syncthreads();  // protect hm from previous iteration's readers
        float h1a = 0.f, h1b = 0.f;
        if (n < N) {
            const float* h1 = H1 + (size_t)n * HIDF;
            const float* h2 = H2 + (size_t)n * HIDF;
            const float* h3 = H3 + (size_t)n * HIDF;
            h1a = fmaxf(h1[l], 0.f);       h1b = fmaxf(h1[l + 64], 0.f);
            float h2a = fmaxf(h2[l], 0.f), h2b = fmaxf(h2[l + 64], 0.f);
            float h3a = fmaxf(h3[l], 0.f), h3b = fmaxf(h3[l + 64], 0.f);
            float s1 = h1a * WaS[l] + h1b * WaS[l + 64];
            float s2 = h2a * WaS[l] + h2b * WaS[l + 64];
            float s3 = h3a * WaS[l] + h3b * WaS[l + 64];
            #pragma unroll
            for (int off = 32; off; off >>= 1) {
                s1 += __shfl_xor(s1, off);
                s2 += __shfl_xor(s2, off);
                s3 += __shfl_xor(s3, off);
            }
            s1 += bav; s2 += bav; s3 += bav;
            float m  = fmaxf(s1, fmaxf(s2, s3));
            float e1 = expf(s1 - m), e2 = expf(s2 - m), e3 = expf(s3 - m);
            float inv = 1.f / (e1 + e2 + e3);
            float w1 = e1 * inv, w2 = e2 * inv, w3 = e3 * inv;
            // h_out = h_meta + h1
            hm[w][l]      = w1 * h1a + w2 * h2a + w3 * h3a + h1a;
            hm[w][l + 64] = w1 * h1b + w2 * h2b + w3 * h3b + h1b;
        }
        __syncthreads();
        if (n < N) {
            float acc = bfv;
            #pragma unroll
            for (int k = 0; k < HIDF; ++k) acc = fmaf(hm[w][k], WfS[k * OUTF + l], acc);
            out[(size_t)n * OUTF + l] = acc;
        }
    }
}

// ---------------- launch ----------------
extern "C" void kernel_launch(void* const* d_in, const int* in_sizes, int n_in,
                              void* d_out, int out_size, void* d_ws, size_t ws_size,
                              hipStream_t stream) {
    const float* x   = (const float*)d_in[0];
    const int*   ei  = (const int*)d_in[1];
    const float *W1  = (const float*)d_in[2],  *b1  = (const float*)d_in[3];
    const float *W21 = (const float*)d_in[4],  *b21 = (const float*)d_in[5];
    const float *W22 = (const float*)d_in[6],  *b22 = (const float*)d_in[7];
    const float *W31 = (const float*)d_in[8],  *b31 = (const float*)d_in[9];
    const float *W32 = (const float*)d_in[10], *b32 = (const float*)d_in[11];
    const float *W33 = (const float*)d_in[12], *b33 = (const float*)d_in[13];
    const float *Wa  = (const float*)d_in[14], *ba  = (const float*)d_in[15];
    const float *Wf  = (const float*)d_in[16], *bfb = (const float*)d_in[17];

    const int N = in_sizes[0] / HIDF;
    const int E = in_sizes[1] / 2;

    // workspace layout (fp32): DINV[N] | T[N*128] | H1 | H2 | H3
    float* DINV = (float*)d_ws;
    float* T    = DINV + N;
    float* H1   = T  + (size_t)N * HIDF;
    float* H2   = H1 + (size_t)N * HIDF;
    float* H3   = H2 + (size_t)N * HIDF;

    const int gN   = (N + 255) / 256;
    const int gE   = (E + 255) / 256;
    const int gAI  = (N * (HIDF / 4) + 255) / 256;
    const int gAE  = (int)(((long)E * 32 + 255) / 256);
    const int gGEMM = 1024;
    const int gMETA = 2048;

    deg_zero<<<gN, 256, 0, stream>>>(DINV, N);
    deg_count<<<gE, 256, 0, stream>>>(ei, DINV, E);
    deg_fin<<<gN, 256, 0, stream>>>(DINV, N);

    // h1 = gcn(x, W1, b1)
    gemm128<false><<<gGEMM, 256, 0, stream>>>(x, W1, T, N);
    agg_init<<<gAI, 256, 0, stream>>>(T, DINV, b1, H1, N);
    agg_edge<<<gAE, 256, 0, stream>>>(T, DINV, ei, H1, E);

    // h2 = gcn(relu(gcn(x, W21, b21)), W22, b22)
    gemm128<false><<<gGEMM, 256, 0, stream>>>(x, W21, T, N);
    agg_init<<<gAI, 256, 0, stream>>>(T, DINV, b21, H2, N);
    agg_edge<<<gAE, 256, 0, stream>>>(T, DINV, ei, H2, E);

    gemm128<true><<<gGEMM, 256, 0, stream>>>(H2, W22, T, N);
    agg_init<<<gAI, 256, 0, stream>>>(T, DINV, b22, H2, N);
    agg_edge<<<gAE, 256, 0, stream>>>(T, DINV, ei, H2, E);

    // h3 chain
    gemm128<false><<<gGEMM, 256, 0, stream>>>(x, W31, T, N);
    agg_init<<<gAI, 256, 0, stream>>>(T, DINV, b31, H3, N);
    agg_edge<<<gAE, 256, 0, stream>>>(T, DINV, ei, H3, E);

    gemm128<true><<<gGEMM, 256, 0, stream>>>(H3, W32, T, N);
    agg_init<<<gAI, 256, 0, stream>>>(T, DINV, b32, H3, N);
    agg_edge<<<gAE, 256, 0, stream>>>(T, DINV, ei, H3, E);

    gemm128<true><<<gGEMM, 256, 0, stream>>>(H3, W33, T, N);
    agg_init<<<gAI, 256, 0, stream>>>(T, DINV, b33, H3, N);
    agg_edge<<<gAE, 256, 0, stream>>>(T, DINV, ei, H3, E);

    // meta combine + final projection
    meta_kernel<<<gMETA, 256, 0, stream>>>(H1, H2, H3, Wa, ba, Wf, bfb,
                                           (float*)d_out, N);
}

// Round 4
// 2329.312 us; speedup vs baseline: 7.4069x; 7.4069x over previous
//
#include <hip/hip_runtime.h>
#include <hip/hip_bf16.h>

#define HIDF 128
#define OUTF 64

// ---------------- degree / CSR build ----------------
__global__ __launch_bounds__(256) void deg_zero(int* __restrict__ d, int N) {
    int i = blockIdx.x * 256 + threadIdx.x;
    if (i < N) d[i] = 0;
}

__global__ __launch_bounds__(256) void deg_count(const int* __restrict__ ei, int* __restrict__ d, int E) {
    int e = blockIdx.x * 256 + threadIdx.x;
    if (e < E) atomicAdd(&d[ei[E + e]], 1);
}

// single block, 1024 threads: exclusive scan of degi -> cursor (row starts), dinv = rsqrt(deg+1)
__global__ __launch_bounds__(1024) void scan_kernel(const int* __restrict__ degi,
                                                    int* __restrict__ cursor,
                                                    float* __restrict__ dinv, int N) {
    __shared__ int ps[1024];
    const int t = threadIdx.x;
    const int C = (N + 1023) / 1024;
    const int lo = t * C;
    const int hi = min(lo + C, N);
    int s = 0;
    for (int i = lo; i < hi; ++i) s += degi[i];
    ps[t] = s;
    __syncthreads();
    for (int off = 1; off < 1024; off <<= 1) {
        int v = ps[t];
        int u = (t >= off) ? ps[t - off] : 0;
        __syncthreads();
        ps[t] = v + u;
        __syncthreads();
    }
    int base = (t == 0) ? 0 : ps[t - 1];
    for (int i = lo; i < hi; ++i) {
        int d = degi[i];
        cursor[i] = base;
        base += d;
        dinv[i] = rsqrtf((float)d + 1.f);
    }
}

// scatter edges into CSR buckets; afterwards cursor[n] == row_end(n)
__global__ __launch_bounds__(256) void scatter_kernel(const int* __restrict__ ei,
                                                      int* __restrict__ cursor,
                                                      int* __restrict__ csr_src, int E) {
    int e = blockIdx.x * 256 + threadIdx.x;
    if (e >= E) return;
    int pos = atomicAdd(&cursor[ei[E + e]], 1);
    csr_src[pos] = ei[e];
}

// ---------------- CSR aggregation: O[n,:] = dinv[n]*( sum_src T[src,:]*dinv[src] + T[n,:]*dinv[n] )
// one wave per node; lane owns 2 contiguous floats
__global__ __launch_bounds__(256) void agg_csr(const float* __restrict__ T,
                                               const float* __restrict__ dinv,
                                               const int* __restrict__ csr_src,
                                               const int* __restrict__ rend,
                                               float* __restrict__ O, int N) {
    const int n = (blockIdx.x * 256 + threadIdx.x) >> 6;
    const int lane = threadIdx.x & 63;
    if (n >= N) return;
    const int start = (n == 0) ? 0 : rend[n - 1];
    const int end   = rend[n];
    const float2* Tv = (const float2*)T;
    float2 acc = make_float2(0.f, 0.f);
    for (int e = start; e < end; ++e) {
        int s = csr_src[e];
        float w = dinv[s];
        float2 v = Tv[s * 64 + lane];
        acc.x = fmaf(v.x, w, acc.x);
        acc.y = fmaf(v.y, w, acc.y);
    }
    const float dv = dinv[n];
    float2 sv = Tv[n * 64 + lane];
    acc.x = fmaf(sv.x, dv, acc.x);
    acc.y = fmaf(sv.y, dv, acc.y);
    float2 o;
    o.x = acc.x * dv;
    o.y = acc.y * dv;
    ((float2*)O)[(size_t)n * 64 + lane] = o;
}

// ---------------- GEMM: T[N,128] = X @ W + b, optional relu  (fp32; W via L1, X tile in LDS) ----------------
template <bool RELU_OUT>
__global__ __launch_bounds__(256) void gemm128b(const float* __restrict__ X,
                                                const float* __restrict__ W,
                                                const float* __restrict__ bias,
                                                float* __restrict__ T, int N) {
    __shared__ float Xs[8][HIDF];               // 4 KB
    const int tid = threadIdx.x;
    const int j4  = tid & 31;   // 4-column group
    const int sub = tid >> 5;   // 0..7 node within group
    const int ngroups = (N + 7) >> 3;
    const float4* Wrow = (const float4*)W;      // row k -> Wrow[k*32 + j4]
    const float4 bv = ((const float4*)bias)[j4];

    for (int g = blockIdx.x; g < ngroups; g += gridDim.x) {
        const int nb = g << 3;
        __syncthreads();  // protect Xs from previous iteration's readers
        for (int i = tid; i < 8 * HIDF; i += 256) {
            int n = nb + (i >> 7);
            int k = i & 127;
            Xs[i >> 7][k] = (n < N) ? X[(size_t)n * HIDF + k] : 0.f;
        }
        __syncthreads();
        const int n = nb + sub;
        float4 acc = make_float4(bv.x, bv.y, bv.z, bv.w);
        #pragma unroll 8
        for (int k = 0; k < HIDF; ++k) {
            float x = Xs[sub][k];
            float4 w = Wrow[k * 32 + j4];
            acc.x = fmaf(x, w.x, acc.x);
            acc.y = fmaf(x, w.y, acc.y);
            acc.z = fmaf(x, w.z, acc.z);
            acc.w = fmaf(x, w.w, acc.w);
        }
        if (RELU_OUT) {
            acc.x = fmaxf(acc.x, 0.f); acc.y = fmaxf(acc.y, 0.f);
            acc.z = fmaxf(acc.z, 0.f); acc.w = fmaxf(acc.w, 0.f);
        }
        if (n < N) *((float4*)&T[(size_t)n * HIDF + j4 * 4]) = acc;
    }
}

// ---------------- meta: scores -> softmax -> weighted sum + h1 residual -> @Wf + bf ----------------
__global__ __launch_bounds__(256) void meta_kernel(const float* __restrict__ H1,
                                                   const float* __restrict__ H2,
                                                   const float* __restrict__ H3,
                                                   const float* __restrict__ Wa,
                                                   const float* __restrict__ ba,
                                                   const float* __restrict__ Wf,
                                                   const float* __restrict__ bfb,
                                                   float* __restrict__ out, int N) {
    __shared__ float WfS[HIDF * OUTF];  // 32 KB
    __shared__ float WaS[HIDF];
    __shared__ float hm[4][HIDF];
    const int tid = threadIdx.x;
    for (int i = tid; i < HIDF * OUTF; i += 256) WfS[i] = Wf[i];
    if (tid < HIDF) WaS[tid] = Wa[tid];
    __syncthreads();
    const float bav = ba[0];
    const int w = tid >> 6;   // node within group of 4
    const int l = tid & 63;   // lane
    const float bfv = bfb[l];
    const int iters = (N + 3) >> 2;

    for (int it = blockIdx.x; it < iters; it += gridDim.x) {
        const int n = it * 4 + w;
        __syncthreads();  // protect hm from previous iteration's readers
        if (n < N) {
            const float* h1 = H1 + (size_t)n * HIDF;
            const float* h2 = H2 + (size_t)n * HIDF;
            const float* h3 = H3 + (size_t)n * HIDF;
            float h1a = fmaxf(h1[l], 0.f), h1b = fmaxf(h1[l + 64], 0.f);
            float h2a = fmaxf(h2[l], 0.f), h2b = fmaxf(h2[l + 64], 0.f);
            float h3a = fmaxf(h3[l], 0.f), h3b = fmaxf(h3[l + 64], 0.f);
            float s1 = h1a * WaS[l] + h1b * WaS[l + 64];
            float s2 = h2a * WaS[l] + h2b * WaS[l + 64];
            float s3 = h3a * WaS[l] + h3b * WaS[l + 64];
            #pragma unroll
            for (int off = 32; off; off >>= 1) {
                s1 += __shfl_xor(s1, off);
                s2 += __shfl_xor(s2, off);
                s3 += __shfl_xor(s3, off);
            }
            s1 += bav; s2 += bav; s3 += bav;
            float m  = fmaxf(s1, fmaxf(s2, s3));
            float e1 = expf(s1 - m), e2 = expf(s2 - m), e3 = expf(s3 - m);
            float inv = 1.f / (e1 + e2 + e3);
            float w1 = e1 * inv, w2 = e2 * inv, w3 = e3 * inv;
            hm[w][l]      = w1 * h1a + w2 * h2a + w3 * h3a + h1a;
            hm[w][l + 64] = w1 * h1b + w2 * h2b + w3 * h3b + h1b;
        }
        __syncthreads();
        if (n < N) {
            float acc = bfv;
            #pragma unroll
            for (int k = 0; k < HIDF; ++k) acc = fmaf(hm[w][k], WfS[k * OUTF + l], acc);
            out[(size_t)n * OUTF + l] = acc;
        }
    }
}

// ---------------- launch ----------------
extern "C" void kernel_launch(void* const* d_in, const int* in_sizes, int n_in,
                              void* d_out, int out_size, void* d_ws, size_t ws_size,
                              hipStream_t stream) {
    const float* x   = (const float*)d_in[0];
    const int*   ei  = (const int*)d_in[1];
    const float *W1  = (const float*)d_in[2],  *b1  = (const float*)d_in[3];
    const float *W21 = (const float*)d_in[4],  *b21 = (const float*)d_in[5];
    const float *W22 = (const float*)d_in[6],  *b22 = (const float*)d_in[7];
    const float *W31 = (const float*)d_in[8],  *b31 = (const float*)d_in[9];
    const float *W32 = (const float*)d_in[10], *b32 = (const float*)d_in[11];
    const float *W33 = (const float*)d_in[12], *b33 = (const float*)d_in[13];
    const float *Wa  = (const float*)d_in[14], *ba  = (const float*)d_in[15];
    const float *Wf  = (const float*)d_in[16], *bfb = (const float*)d_in[17];

    const int N = in_sizes[0] / HIDF;
    const int E = in_sizes[1] / 2;

    // workspace layout: ints first, then 4 big fp32 buffers
    int*   DEGI    = (int*)d_ws;                    // N
    int*   CURSOR  = DEGI + N;                      // N (row starts -> row ends)
    int*   CSR_SRC = CURSOR + N;                    // E
    float* DINV    = (float*)(CSR_SRC + E);         // N
    float* PX      = DINV + N;                      // N*128
    float* BB      = PX + (size_t)N * HIDF;         // N*128 (scratch; becomes H1)
    float* H2      = BB + (size_t)N * HIDF;         // N*128
    float* H3      = H2 + (size_t)N * HIDF;         // N*128

    const int gN    = (N + 255) / 256;
    const int gE    = (E + 255) / 256;
    const int gAGG  = (N * 64 + 255) / 256;   // one wave per node
    const int gGEMM = 1024;
    const int gMETA = 2048;

    // CSR build
    deg_zero<<<gN, 256, 0, stream>>>(DEGI, N);
    deg_count<<<gE, 256, 0, stream>>>(ei, DEGI, E);
    scan_kernel<<<1, 1024, 0, stream>>>(DEGI, CURSOR, DINV, N);
    scatter_kernel<<<gE, 256, 0, stream>>>(ei, CURSOR, CSR_SRC, E);

    // shared propagation of x
    agg_csr<<<gAGG, 256, 0, stream>>>(x, DINV, CSR_SRC, CURSOR, PX, N);

    // h2 chain: g2 = relu(PX@W21+b21) -> H2 ; BB = P g2 ; H2 = BB@W22+b22
    gemm128b<true ><<<gGEMM, 256, 0, stream>>>(PX, W21, b21, H2, N);
    agg_csr<<<gAGG, 256, 0, stream>>>(H2, DINV, CSR_SRC, CURSOR, BB, N);
    gemm128b<false><<<gGEMM, 256, 0, stream>>>(BB, W22, b22, H2, N);

    // h3 chain: g3 = relu(PX@W31+b31) -> H3 ; BB = P g3 ; H3 = relu(BB@W32+b32)
    //           BB = P H3 ; H3 = BB@W33+b33
    gemm128b<true ><<<gGEMM, 256, 0, stream>>>(PX, W31, b31, H3, N);
    agg_csr<<<gAGG, 256, 0, stream>>>(H3, DINV, CSR_SRC, CURSOR, BB, N);
    gemm128b<true ><<<gGEMM, 256, 0, stream>>>(BB, W32, b32, H3, N);
    agg_csr<<<gAGG, 256, 0, stream>>>(H3, DINV, CSR_SRC, CURSOR, BB, N);
    gemm128b<false><<<gGEMM, 256, 0, stream>>>(BB, W33, b33, H3, N);

    // h1 last: H1 (=BB) = PX@W1+b1   (PX free afterwards)
    gemm128b<false><<<gGEMM, 256, 0, stream>>>(PX, W1, b1, BB, N);

    // meta combine + final projection
    meta_kernel<<<gMETA, 256, 0, stream>>>(BB, H2, H3, Wa, ba, Wf, bfb,
                                           (float*)d_out, N);
}

// Round 6
// 1288.894 us; speedup vs baseline: 13.3859x; 1.8072x over previous
//
#include <hip/hip_runtime.h>
#include <hip/hip_bf16.h>

#define HIDF 128
#define OUTF 64
#define SCAN_B 256   // blocks in hierarchical scan

// ---------------- degree / CSR build ----------------
__global__ __launch_bounds__(256) void deg_zero(int* __restrict__ d, int N) {
    int i = blockIdx.x * 256 + threadIdx.x;
    if (i < N) d[i] = 0;
}

__global__ __launch_bounds__(256) void deg_count(const int* __restrict__ ei, int* __restrict__ d, int E) {
    int e = blockIdx.x * 256 + threadIdx.x;
    if (e < E) atomicAdd(&d[ei[E + e]], 1);
}

// per-block degree sums
__global__ __launch_bounds__(256) void scanA(const int* __restrict__ degi, int* __restrict__ blocksum, int N) {
    __shared__ int red[256];
    const int b = blockIdx.x;
    const int chunk = (N + SCAN_B - 1) / SCAN_B;
    const int lo = b * chunk, hi = min(lo + chunk, N);
    int s = 0;
    for (int i = lo + threadIdx.x; i < hi; i += 256) s += degi[i];
    red[threadIdx.x] = s;
    __syncthreads();
    for (int off = 128; off; off >>= 1) {
        if (threadIdx.x < off) red[threadIdx.x] += red[threadIdx.x + off];
        __syncthreads();
    }
    if (threadIdx.x == 0) blocksum[b] = red[0];
}

// exclusive scan of the 256 block sums (1 block)
__global__ __launch_bounds__(256) void scanB(const int* __restrict__ blocksum, int* __restrict__ blockoff) {
    __shared__ int ps[256];
    const int t = threadIdx.x;
    ps[t] = blocksum[t];
    __syncthreads();
    for (int off = 1; off < 256; off <<= 1) {
        int v = ps[t];
        int u = (t >= off) ? ps[t - off] : 0;
        __syncthreads();
        ps[t] = v + u;
        __syncthreads();
    }
    blockoff[t] = (t == 0) ? 0 : ps[t - 1];
}

// per-element cursor (row starts) + dinv
__global__ __launch_bounds__(256) void scanC(const int* __restrict__ degi,
                                             const int* __restrict__ blockoff,
                                             int* __restrict__ cursor,
                                             float* __restrict__ dinv, int N) {
    __shared__ int ps[256];
    const int b = blockIdx.x;
    const int chunk = (N + SCAN_B - 1) / SCAN_B;
    const int lo = b * chunk, hi = min(lo + chunk, N);
    const int tchunk = (chunk + 255) / 256;
    const int tlo = lo + threadIdx.x * tchunk;
    const int thi = min(tlo + tchunk, hi);
    int s = 0;
    for (int i = tlo; i < thi; ++i) s += degi[i];
    ps[threadIdx.x] = s;
    __syncthreads();
    for (int off = 1; off < 256; off <<= 1) {
        int v = ps[threadIdx.x];
        int u = (threadIdx.x >= off) ? ps[threadIdx.x - off] : 0;
        __syncthreads();
        ps[threadIdx.x] = v + u;
        __syncthreads();
    }
    int base = blockoff[b] + ((threadIdx.x == 0) ? 0 : ps[threadIdx.x - 1]);
    for (int i = tlo; i < thi; ++i) {
        int d = degi[i];
        cursor[i] = base;
        base += d;
        dinv[i] = rsqrtf((float)d + 1.f);
    }
}

// scatter edges into CSR buckets; afterwards cursor[n] == row_end(n)
__global__ __launch_bounds__(256) void scatter_kernel(const int* __restrict__ ei,
                                                      int* __restrict__ cursor,
                                                      int* __restrict__ csr_src, int E) {
    int e = blockIdx.x * 256 + threadIdx.x;
    if (e >= E) return;
    int pos = atomicAdd(&cursor[ei[E + e]], 1);
    csr_src[pos] = ei[e];
}

// ---------------- CSR aggregation: O[n,:] = dinv[n]*( sum_src T[src,:]*dinv[src] + T[n,:]*dinv[n] )
__global__ __launch_bounds__(256) void agg_csr(const float* __restrict__ T,
                                               const float* __restrict__ dinv,
                                               const int* __restrict__ csr_src,
                                               const int* __restrict__ rend,
                                               float* __restrict__ O, int N) {
    const int n = (blockIdx.x * 256 + threadIdx.x) >> 6;
    const int lane = threadIdx.x & 63;
    if (n >= N) return;
    const int start = (n == 0) ? 0 : rend[n - 1];
    const int end   = rend[n];
    const float2* Tv = (const float2*)T;
    float2 acc = make_float2(0.f, 0.f);
    for (int e = start; e < end; ++e) {
        int s = csr_src[e];
        float w = dinv[s];
        float2 v = Tv[s * 64 + lane];
        acc.x = fmaf(v.x, w, acc.x);
        acc.y = fmaf(v.y, w, acc.y);
    }
    const float dv = dinv[n];
    float2 sv = Tv[n * 64 + lane];
    acc.x = fmaf(sv.x, dv, acc.x);
    acc.y = fmaf(sv.y, dv, acc.y);
    float2 o;
    o.x = acc.x * dv;
    o.y = acc.y * dv;
    ((float2*)O)[(size_t)n * 64 + lane] = o;
}

// ---------------- GEMM: T[N,128] = X @ W + b, optional relu
// 64-node tile; X transposed in LDS; each thread: 8 nodes x 4 cols (W float4 reused 8x)
template <bool RELU_OUT>
__global__ __launch_bounds__(256) void gemm128c(const float* __restrict__ X,
                                                const float* __restrict__ W,
                                                const float* __restrict__ bias,
                                                float* __restrict__ T, int N) {
    __shared__ float Xs[HIDF][68];   // transposed tile, padded (16B-aligned rows)
    const int tid = threadIdx.x;
    const int nb = blockIdx.x * 64;

    // load tile: thread -> node nloc = tid&63; 4 threads/node each cover 8 of 32 float4-quads
    {
        const int nloc = tid & 63;
        const int n = nb + nloc;
        const int kq0 = tid >> 6;   // 0..3
        if (n < N) {
            const float4* Xr = (const float4*)(X + (size_t)n * HIDF);
            #pragma unroll
            for (int kq = kq0; kq < 32; kq += 4) {
                float4 v = Xr[kq];
                int k = kq * 4;
                Xs[k + 0][nloc] = v.x;
                Xs[k + 1][nloc] = v.y;
                Xs[k + 2][nloc] = v.z;
                Xs[k + 3][nloc] = v.w;
            }
        } else {
            #pragma unroll
            for (int kq = kq0; kq < 32; kq += 4) {
                int k = kq * 4;
                Xs[k + 0][nloc] = 0.f; Xs[k + 1][nloc] = 0.f;
                Xs[k + 2][nloc] = 0.f; Xs[k + 3][nloc] = 0.f;
            }
        }
    }
    __syncthreads();

    const int j4  = tid & 31;   // 4-column group
    const int sub = tid >> 5;   // owns nodes sub*8 .. sub*8+7
    const float4* Wrow = (const float4*)W;
    const float4 bv = ((const float4*)bias)[j4];

    float4 acc[8];
    #pragma unroll
    for (int i = 0; i < 8; ++i) acc[i] = bv;

    #pragma unroll 4
    for (int k = 0; k < HIDF; ++k) {
        float4 w = Wrow[k * 32 + j4];
        float xv[8];
        *(float4*)&xv[0] = *(const float4*)&Xs[k][sub * 8];
        *(float4*)&xv[4] = *(const float4*)&Xs[k][sub * 8 + 4];
        #pragma unroll
        for (int i = 0; i < 8; ++i) {
            acc[i].x = fmaf(xv[i], w.x, acc[i].x);
            acc[i].y = fmaf(xv[i], w.y, acc[i].y);
            acc[i].z = fmaf(xv[i], w.z, acc[i].z);
            acc[i].w = fmaf(xv[i], w.w, acc[i].w);
        }
    }

    #pragma unroll
    for (int i = 0; i < 8; ++i) {
        int n = nb + sub * 8 + i;
        if (n < N) {
            float4 o = acc[i];
            if (RELU_OUT) {
                o.x = fmaxf(o.x, 0.f); o.y = fmaxf(o.y, 0.f);
                o.z = fmaxf(o.z, 0.f); o.w = fmaxf(o.w, 0.f);
            }
            *((float4*)&T[(size_t)n * HIDF + j4 * 4]) = o;
        }
    }
}

// ---------------- meta: scores -> softmax -> weighted sum + h1 residual -> @Wf + bf ----------------
__global__ __launch_bounds__(256) void meta_kernel(const float* __restrict__ H1,
                                                   const float* __restrict__ H2,
                                                   const float* __restrict__ H3,
                                                   const float* __restrict__ Wa,
                                                   const float* __restrict__ ba,
                                                   const float* __restrict__ Wf,
                                                   const float* __restrict__ bfb,
                                                   float* __restrict__ out, int N) {
    __shared__ float WfS[HIDF * OUTF];  // 32 KB
    __shared__ float WaS[HIDF];
    __shared__ float hm[4][HIDF];
    const int tid = threadIdx.x;
    for (int i = tid; i < HIDF * OUTF; i += 256) WfS[i] = Wf[i];
    if (tid < HIDF) WaS[tid] = Wa[tid];
    __syncthreads();
    const float bav = ba[0];
    const int w = tid >> 6;   // node within group of 4
    const int l = tid & 63;   // lane
    const float bfv = bfb[l];
    const int iters = (N + 3) >> 2;

    for (int it = blockIdx.x; it < iters; it += gridDim.x) {
        const int n = it * 4 + w;
        __syncthreads();  // protect hm from previous iteration's readers
        if (n < N) {
            const float* h1 = H1 + (size_t)n * HIDF;
            const float* h2 = H2 + (size_t)n * HIDF;
            const float* h3 = H3 + (size_t)n * HIDF;
            float h1a = fmaxf(h1[l], 0.f), h1b = fmaxf(h1[l + 64], 0.f);
            float h2a = fmaxf(h2[l], 0.f), h2b = fmaxf(h2[l + 64], 0.f);
            float h3a = fmaxf(h3[l], 0.f), h3b = fmaxf(h3[l + 64], 0.f);
            float s1 = h1a * WaS[l] + h1b * WaS[l + 64];
            float s2 = h2a * WaS[l] + h2b * WaS[l + 64];
            float s3 = h3a * WaS[l] + h3b * WaS[l + 64];
            #pragma unroll
            for (int off = 32; off; off >>= 1) {
                s1 += __shfl_xor(s1, off);
                s2 += __shfl_xor(s2, off);
                s3 += __shfl_xor(s3, off);
            }
            s1 += bav; s2 += bav; s3 += bav;
            float m  = fmaxf(s1, fmaxf(s2, s3));
            float e1 = expf(s1 - m), e2 = expf(s2 - m), e3 = expf(s3 - m);
            float inv = 1.f / (e1 + e2 + e3);
            float w1 = e1 * inv, w2 = e2 * inv, w3 = e3 * inv;
            hm[w][l]      = w1 * h1a + w2 * h2a + w3 * h3a + h1a;
            hm[w][l + 64] = w1 * h1b + w2 * h2b + w3 * h3b + h1b;
        }
        __syncthreads();
        if (n < N) {
            float acc = bfv;
            #pragma unroll
            for (int k = 0; k < HIDF; ++k) acc = fmaf(hm[w][k], WfS[k * OUTF + l], acc);
            out[(size_t)n * OUTF + l] = acc;
        }
    }
}

// ---------------- launch ----------------
extern "C" void kernel_launch(void* const* d_in, const int* in_sizes, int n_in,
                              void* d_out, int out_size, void* d_ws, size_t ws_size,
                              hipStream_t stream) {
    const float* x   = (const float*)d_in[0];
    const int*   ei  = (const int*)d_in[1];
    const float *W1  = (const float*)d_in[2],  *b1  = (const float*)d_in[3];
    const float *W21 = (const float*)d_in[4],  *b21 = (const float*)d_in[5];
    const float *W22 = (const float*)d_in[6],  *b22 = (const float*)d_in[7];
    const float *W31 = (const float*)d_in[8],  *b31 = (const float*)d_in[9];
    const float *W32 = (const float*)d_in[10], *b32 = (const float*)d_in[11];
    const float *W33 = (const float*)d_in[12], *b33 = (const float*)d_in[13];
    const float *Wa  = (const float*)d_in[14], *ba  = (const float*)d_in[15];
    const float *Wf  = (const float*)d_in[16], *bfb = (const float*)d_in[17];

    const int N = in_sizes[0] / HIDF;
    const int E = in_sizes[1] / 2;

    // workspace layout: ints first, then fp32 buffers
    int*   DEGI    = (int*)d_ws;                    // N
    int*   CURSOR  = DEGI + N;                      // N (row starts -> row ends)
    int*   CSR_SRC = CURSOR + N;                    // E
    int*   BSUM    = CSR_SRC + E;                   // 256
    int*   BOFF    = BSUM + 256;                    // 256
    float* DINV    = (float*)(BOFF + 256);          // N
    float* PX      = DINV + N;                      // N*128
    float* BB      = PX + (size_t)N * HIDF;         // N*128 (scratch; becomes H1)
    float* H2      = BB + (size_t)N * HIDF;         // N*128
    float* H3      = H2 + (size_t)N * HIDF;         // N*128

    const int gN    = (N + 255) / 256;
    const int gE    = (E + 255) / 256;
    const int gAGG  = (N * 64 + 255) / 256;         // one wave per node
    const int gGEMM = (N + 63) / 64;                // one block per 64-node tile
    const int gMETA = 2048;

    // CSR build
    deg_zero<<<gN, 256, 0, stream>>>(DEGI, N);
    deg_count<<<gE, 256, 0, stream>>>(ei, DEGI, E);
    scanA<<<SCAN_B, 256, 0, stream>>>(DEGI, BSUM, N);
    scanB<<<1, 256, 0, stream>>>(BSUM, BOFF);
    scanC<<<SCAN_B, 256, 0, stream>>>(DEGI, BOFF, CURSOR, DINV, N);
    scatter_kernel<<<gE, 256, 0, stream>>>(ei, CURSOR, CSR_SRC, E);

    // shared propagation of x
    agg_csr<<<gAGG, 256, 0, stream>>>(x, DINV, CSR_SRC, CURSOR, PX, N);

    // h2 chain: H2 = relu(PX@W21+b21) ; BB = P H2 ; H2 = BB@W22+b22
    gemm128c<true ><<<gGEMM, 256, 0, stream>>>(PX, W21, b21, H2, N);
    agg_csr<<<gAGG, 256, 0, stream>>>(H2, DINV, CSR_SRC, CURSOR, BB, N);
    gemm128c<false><<<gGEMM, 256, 0, stream>>>(BB, W22, b22, H2, N);

    // h3 chain: H3 = relu(PX@W31+b31) ; BB = P H3 ; H3 = relu(BB@W32+b32) ; BB = P H3 ; H3 = BB@W33+b33
    gemm128c<true ><<<gGEMM, 256, 0, stream>>>(PX, W31, b31, H3, N);
    agg_csr<<<gAGG, 256, 0, stream>>>(H3, DINV, CSR_SRC, CURSOR, BB, N);
    gemm128c<true ><<<gGEMM, 256, 0, stream>>>(BB, W32, b32, H3, N);
    agg_csr<<<gAGG, 256, 0, stream>>>(H3, DINV, CSR_SRC, CURSOR, BB, N);
    gemm128c<false><<<gGEMM, 256, 0, stream>>>(BB, W33, b33, H3, N);

    // h1 last: H1 (=BB) = PX@W1+b1
    gemm128c<false><<<gGEMM, 256, 0, stream>>>(PX, W1, b1, BB, N);

    // meta combine + final projection
    meta_kernel<<<gMETA, 256, 0, stream>>>(BB, H2, H3, Wa, ba, Wf, bfb,
                                           (float*)d_out, N);
}

// Round 7
// 1214.291 us; speedup vs baseline: 14.2084x; 1.0614x over previous
//
#include <hip/hip_runtime.h>
#include <hip/hip_bf16.h>

#define HIDF 128
#define OUTF 64
#define SCAN_B 256   // blocks in hierarchical scan

__device__ __forceinline__ float us2f(unsigned u_lo16) {           // bf16 bits in low 16
    return __uint_as_float(u_lo16 << 16);
}
__device__ __forceinline__ unsigned short f2us(float f) {          // RNE f32 -> bf16 bits
    __hip_bfloat16 h = __float2bfloat16(f);
    return *reinterpret_cast<unsigned short*>(&h);
}

// ---------------- degree / CSR build ----------------
__global__ __launch_bounds__(256) void deg_zero(int* __restrict__ d, int N) {
    int i = blockIdx.x * 256 + threadIdx.x;
    if (i < N) d[i] = 0;
}

__global__ __launch_bounds__(256) void deg_count(const int* __restrict__ ei, int* __restrict__ d, int E) {
    int e = blockIdx.x * 256 + threadIdx.x;
    if (e < E) atomicAdd(&d[ei[E + e]], 1);
}

__global__ __launch_bounds__(256) void scanA(const int* __restrict__ degi, int* __restrict__ blocksum, int N) {
    __shared__ int red[256];
    const int b = blockIdx.x;
    const int chunk = (N + SCAN_B - 1) / SCAN_B;
    const int lo = b * chunk, hi = min(lo + chunk, N);
    int s = 0;
    for (int i = lo + threadIdx.x; i < hi; i += 256) s += degi[i];
    red[threadIdx.x] = s;
    __syncthreads();
    for (int off = 128; off; off >>= 1) {
        if (threadIdx.x < off) red[threadIdx.x] += red[threadIdx.x + off];
        __syncthreads();
    }
    if (threadIdx.x == 0) blocksum[b] = red[0];
}

__global__ __launch_bounds__(256) void scanB(const int* __restrict__ blocksum, int* __restrict__ blockoff) {
    __shared__ int ps[256];
    const int t = threadIdx.x;
    ps[t] = blocksum[t];
    __syncthreads();
    for (int off = 1; off < 256; off <<= 1) {
        int v = ps[t];
        int u = (t >= off) ? ps[t - off] : 0;
        __syncthreads();
        ps[t] = v + u;
        __syncthreads();
    }
    blockoff[t] = (t == 0) ? 0 : ps[t - 1];
}

__global__ __launch_bounds__(256) void scanC(const int* __restrict__ degi,
                                             const int* __restrict__ blockoff,
                                             int* __restrict__ cursor,
                                             float* __restrict__ dinv, int N) {
    __shared__ int ps[256];
    const int b = blockIdx.x;
    const int chunk = (N + SCAN_B - 1) / SCAN_B;
    const int lo = b * chunk, hi = min(lo + chunk, N);
    const int tchunk = (chunk + 255) / 256;
    const int tlo = lo + threadIdx.x * tchunk;
    const int thi = min(tlo + tchunk, hi);
    int s = 0;
    for (int i = tlo; i < thi; ++i) s += degi[i];
    ps[threadIdx.x] = s;
    __syncthreads();
    for (int off = 1; off < 256; off <<= 1) {
        int v = ps[threadIdx.x];
        int u = (threadIdx.x >= off) ? ps[threadIdx.x - off] : 0;
        __syncthreads();
        ps[threadIdx.x] = v + u;
        __syncthreads();
    }
    int base = blockoff[b] + ((threadIdx.x == 0) ? 0 : ps[threadIdx.x - 1]);
    for (int i = tlo; i < thi; ++i) {
        int d = degi[i];
        cursor[i] = base;
        base += d;
        dinv[i] = rsqrtf((float)d + 1.f);
    }
}

__global__ __launch_bounds__(256) void scatter_kernel(const int* __restrict__ ei,
                                                      int* __restrict__ cursor,
                                                      int* __restrict__ csr_src, int E) {
    int e = blockIdx.x * 256 + threadIdx.x;
    if (e >= E) return;
    int pos = atomicAdd(&cursor[ei[E + e]], 1);
    csr_src[pos] = ei[e];
}

// ---------------- convert: TB[n,:] = bf16( x[n,:] * dinv[n] ) ----------------
__global__ __launch_bounds__(256) void cvt_scale(const float* __restrict__ X,
                                                 const float* __restrict__ dinv,
                                                 unsigned short* __restrict__ TB, int N) {
    int g = blockIdx.x * 256 + threadIdx.x;   // float4-group index
    if (g >= N * 32) return;
    int n = g >> 5;
    float dv = dinv[n];
    float4 v = ((const float4*)X)[g];
    ushort4 o;
    o.x = f2us(v.x * dv); o.y = f2us(v.y * dv);
    o.z = f2us(v.z * dv); o.w = f2us(v.w * dv);
    ((ushort4*)TB)[g] = o;
}

// ---------------- CSR aggregation over bf16 rows (rows pre-scaled by dinv[src]):
// O[n,:] = dinv[n] * ( sum_src TB[src,:] + TB[n,:] )      (fp32 accumulate, fp32 out)
__global__ __launch_bounds__(256) void agg_b(const unsigned short* __restrict__ TB,
                                             const float* __restrict__ dinv,
                                             const int* __restrict__ csr_src,
                                             const int* __restrict__ rend,
                                             float* __restrict__ O, int N) {
    const int n = (blockIdx.x * 256 + threadIdx.x) >> 6;
    const int lane = threadIdx.x & 63;
    if (n >= N) return;
    const int start = (n == 0) ? 0 : rend[n - 1];
    const int end   = rend[n];
    const unsigned* Tv = (const unsigned*)TB;   // row = 64 uints (2 bf16 each)
    float accx = 0.f, accy = 0.f;
    for (int e = start; e < end; ++e) {
        int s = csr_src[e];
        unsigned v = Tv[(size_t)s * 64 + lane];
        accx += us2f(v & 0xffffu);
        accy += __uint_as_float(v & 0xffff0000u);
    }
    unsigned sv = Tv[(size_t)n * 64 + lane];
    accx += us2f(sv & 0xffffu);
    accy += __uint_as_float(sv & 0xffff0000u);
    const float dv = dinv[n];
    float2 o;
    o.x = accx * dv;
    o.y = accy * dv;
    ((float2*)O)[(size_t)n * 64 + lane] = o;
}

// ---------------- GEMM: out = X @ W + b, with selectable epilogue/output ----------------
// OM_F32: float4 out (no relu)  | OM_BF16: bf16 out (no relu) | OM_BF16_SR: relu, *dinv[n], bf16 out
#define OM_F32 0
#define OM_BF16 1
#define OM_BF16_SR 2
template <int OMODE>
__global__ __launch_bounds__(256) void gemm128d(const float* __restrict__ X,
                                                const float* __restrict__ W,
                                                const float* __restrict__ bias,
                                                const float* __restrict__ dinv,
                                                void* __restrict__ T, int N) {
    __shared__ float Xs[HIDF][68];   // transposed tile, padded
    const int tid = threadIdx.x;
    const int nb = blockIdx.x * 64;

    {   // load tile: node nloc = tid&63; 4 threads/node cover 32 float4-quads
        const int nloc = tid & 63;
        const int n = nb + nloc;
        const int kq0 = tid >> 6;   // 0..3
        if (n < N) {
            const float4* Xr = (const float4*)(X + (size_t)n * HIDF);
            #pragma unroll
            for (int kq = kq0; kq < 32; kq += 4) {
                float4 v = Xr[kq];
                int k = kq * 4;
                Xs[k + 0][nloc] = v.x;
                Xs[k + 1][nloc] = v.y;
                Xs[k + 2][nloc] = v.z;
                Xs[k + 3][nloc] = v.w;
            }
        } else {
            #pragma unroll
            for (int kq = kq0; kq < 32; kq += 4) {
                int k = kq * 4;
                Xs[k + 0][nloc] = 0.f; Xs[k + 1][nloc] = 0.f;
                Xs[k + 2][nloc] = 0.f; Xs[k + 3][nloc] = 0.f;
            }
        }
    }
    __syncthreads();

    const int j4  = tid & 31;   // 4-column group
    const int sub = tid >> 5;   // owns nodes sub*8 .. sub*8+7
    const float4* Wrow = (const float4*)W;
    const float4 bv = ((const float4*)bias)[j4];

    float4 acc[8];
    #pragma unroll
    for (int i = 0; i < 8; ++i) acc[i] = bv;

    #pragma unroll 4
    for (int k = 0; k < HIDF; ++k) {
        float4 w = Wrow[k * 32 + j4];
        float xv[8];
        *(float4*)&xv[0] = *(const float4*)&Xs[k][sub * 8];
        *(float4*)&xv[4] = *(const float4*)&Xs[k][sub * 8 + 4];
        #pragma unroll
        for (int i = 0; i < 8; ++i) {
            acc[i].x = fmaf(xv[i], w.x, acc[i].x);
            acc[i].y = fmaf(xv[i], w.y, acc[i].y);
            acc[i].z = fmaf(xv[i], w.z, acc[i].z);
            acc[i].w = fmaf(xv[i], w.w, acc[i].w);
        }
    }

    #pragma unroll
    for (int i = 0; i < 8; ++i) {
        int n = nb + sub * 8 + i;
        if (n >= N) continue;
        float4 o = acc[i];
        if (OMODE == OM_BF16_SR) {
            float dv = dinv[n];
            o.x = fmaxf(o.x, 0.f) * dv; o.y = fmaxf(o.y, 0.f) * dv;
            o.z = fmaxf(o.z, 0.f) * dv; o.w = fmaxf(o.w, 0.f) * dv;
        }
        if (OMODE == OM_F32) {
            *((float4*)((float*)T + (size_t)n * HIDF + j4 * 4)) = o;
        } else {
            ushort4 u;
            u.x = f2us(o.x); u.y = f2us(o.y); u.z = f2us(o.z); u.w = f2us(o.w);
            *((ushort4*)((unsigned short*)T + (size_t)n * HIDF + j4 * 4)) = u;
        }
    }
}

// ---------------- meta: scores -> softmax -> weighted sum + h1 residual -> @Wf + bf ----------------
__global__ __launch_bounds__(256) void meta_kernel(const float* __restrict__ H1,
                                                   const unsigned short* __restrict__ H2B,
                                                   const unsigned short* __restrict__ H3B,
                                                   const float* __restrict__ Wa,
                                                   const float* __restrict__ ba,
                                                   const float* __restrict__ Wf,
                                                   const float* __restrict__ bfb,
                                                   float* __restrict__ out, int N) {
    __shared__ float WfS[HIDF * OUTF];  // 32 KB
    __shared__ float WaS[HIDF];
    __shared__ float hm[4][HIDF];
    const int tid = threadIdx.x;
    for (int i = tid; i < HIDF * OUTF; i += 256) WfS[i] = Wf[i];
    if (tid < HIDF) WaS[tid] = Wa[tid];
    __syncthreads();
    const float bav = ba[0];
    const int w = tid >> 6;   // node within group of 4
    const int l = tid & 63;   // lane
    const float bfv = bfb[l];
    const int iters = (N + 3) >> 2;

    for (int it = blockIdx.x; it < iters; it += gridDim.x) {
        const int n = it * 4 + w;
        __syncthreads();  // protect hm from previous iteration's readers
        if (n < N) {
            const float* h1 = H1 + (size_t)n * HIDF;
            const unsigned short* h2 = H2B + (size_t)n * HIDF;
            const unsigned short* h3 = H3B + (size_t)n * HIDF;
            float h1a = fmaxf(h1[l], 0.f),            h1b = fmaxf(h1[l + 64], 0.f);
            float h2a = fmaxf(us2f(h2[l]), 0.f),      h2b = fmaxf(us2f(h2[l + 64]), 0.f);
            float h3a = fmaxf(us2f(h3[l]), 0.f),      h3b = fmaxf(us2f(h3[l + 64]), 0.f);
            float s1 = h1a * WaS[l] + h1b * WaS[l + 64];
            float s2 = h2a * WaS[l] + h2b * WaS[l + 64];
            float s3 = h3a * WaS[l] + h3b * WaS[l + 64];
            #pragma unroll
            for (int off = 32; off; off >>= 1) {
                s1 += __shfl_xor(s1, off);
                s2 += __shfl_xor(s2, off);
                s3 += __shfl_xor(s3, off);
            }
            s1 += bav; s2 += bav; s3 += bav;
            float m  = fmaxf(s1, fmaxf(s2, s3));
            float e1 = expf(s1 - m), e2 = expf(s2 - m), e3 = expf(s3 - m);
            float inv = 1.f / (e1 + e2 + e3);
            float w1 = e1 * inv, w2 = e2 * inv, w3 = e3 * inv;
            hm[w][l]      = w1 * h1a + w2 * h2a + w3 * h3a + h1a;
            hm[w][l + 64] = w1 * h1b + w2 * h2b + w3 * h3b + h1b;
        }
        __syncthreads();
        if (n < N) {
            float acc = bfv;
            #pragma unroll
            for (int k = 0; k < HIDF; ++k) acc = fmaf(hm[w][k], WfS[k * OUTF + l], acc);
            out[(size_t)n * OUTF + l] = acc;
        }
    }
}

// ---------------- launch ----------------
extern "C" void kernel_launch(void* const* d_in, const int* in_sizes, int n_in,
                              void* d_out, int out_size, void* d_ws, size_t ws_size,
                              hipStream_t stream) {
    const float* x   = (const float*)d_in[0];
    const int*   ei  = (const int*)d_in[1];
    const float *W1  = (const float*)d_in[2],  *b1  = (const float*)d_in[3];
    const float *W21 = (const float*)d_in[4],  *b21 = (const float*)d_in[5];
    const float *W22 = (const float*)d_in[6],  *b22 = (const float*)d_in[7];
    const float *W31 = (const float*)d_in[8],  *b31 = (const float*)d_in[9];
    const float *W32 = (const float*)d_in[10], *b32 = (const float*)d_in[11];
    const float *W33 = (const float*)d_in[12], *b33 = (const float*)d_in[13];
    const float *Wa  = (const float*)d_in[14], *ba  = (const float*)d_in[15];
    const float *Wf  = (const float*)d_in[16], *bfb = (const float*)d_in[17];

    const int N = in_sizes[0] / HIDF;
    const int E = in_sizes[1] / 2;

    // workspace: ints | DINV | TB(bf16) | PX(f32) | AG(f32) | H2B(bf16) | H3B(bf16)   (~187 MB)
    int*   DEGI    = (int*)d_ws;                          // N
    int*   CURSOR  = DEGI + N;                            // N
    int*   CSR_SRC = CURSOR + N;                          // E
    int*   BSUM    = CSR_SRC + E;                         // 256
    int*   BOFF    = BSUM + 256;                          // 256
    float* DINV    = (float*)(BOFF + 256);                // N
    unsigned short* TB = (unsigned short*)(DINV + N);     // N*128 bf16
    float* PX      = (float*)(TB + (size_t)N * HIDF);     // N*128 f32 (becomes H1 in-place)
    float* AG      = PX + (size_t)N * HIDF;               // N*128 f32 (agg scratch)
    unsigned short* H2B = (unsigned short*)(AG + (size_t)N * HIDF);  // N*128 bf16
    unsigned short* H3B = H2B + (size_t)N * HIDF;                    // N*128 bf16

    const int gN    = (N + 255) / 256;
    const int gE    = (E + 255) / 256;
    const int gCVT  = (N * 32 + 255) / 256;
    const int gAGG  = (N * 64 + 255) / 256;         // one wave per node
    const int gGEMM = (N + 63) / 64;
    const int gMETA = 2048;

    // CSR build
    deg_zero<<<gN, 256, 0, stream>>>(DEGI, N);
    deg_count<<<gE, 256, 0, stream>>>(ei, DEGI, E);
    scanA<<<SCAN_B, 256, 0, stream>>>(DEGI, BSUM, N);
    scanB<<<1, 256, 0, stream>>>(BSUM, BOFF);
    scanC<<<SCAN_B, 256, 0, stream>>>(DEGI, BOFF, CURSOR, DINV, N);
    scatter_kernel<<<gE, 256, 0, stream>>>(ei, CURSOR, CSR_SRC, E);

    // TB = bf16(x * dinv); PX = P x  (shared by all three branches)
    cvt_scale<<<gCVT, 256, 0, stream>>>(x, DINV, TB, N);
    agg_b<<<gAGG, 256, 0, stream>>>(TB, DINV, CSR_SRC, CURSOR, PX, N);

    // h2 chain: TB = bf16(relu(PX@W21+b21)*dinv) ; AG = P TB ; H2B = bf16(AG@W22+b22)
    gemm128d<OM_BF16_SR><<<gGEMM, 256, 0, stream>>>(PX, W21, b21, DINV, TB, N);
    agg_b<<<gAGG, 256, 0, stream>>>(TB, DINV, CSR_SRC, CURSOR, AG, N);
    gemm128d<OM_BF16><<<gGEMM, 256, 0, stream>>>(AG, W22, b22, DINV, H2B, N);

    // h3 chain
    gemm128d<OM_BF16_SR><<<gGEMM, 256, 0, stream>>>(PX, W31, b31, DINV, TB, N);
    agg_b<<<gAGG, 256, 0, stream>>>(TB, DINV, CSR_SRC, CURSOR, AG, N);
    gemm128d<OM_BF16_SR><<<gGEMM, 256, 0, stream>>>(AG, W32, b32, DINV, TB, N);
    agg_b<<<gAGG, 256, 0, stream>>>(TB, DINV, CSR_SRC, CURSOR, AG, N);
    gemm128d<OM_BF16><<<gGEMM, 256, 0, stream>>>(AG, W33, b33, DINV, H3B, N);

    // h1: PX <- PX@W1+b1   (in-place: per-block tile fully read into LDS before stores)
    gemm128d<OM_F32><<<gGEMM, 256, 0, stream>>>(PX, W1, b1, DINV, PX, N);

    // meta combine + final projection
    meta_kernel<<<gMETA, 256, 0, stream>>>(PX, H2B, H3B, Wa, ba, Wf, bfb,
                                           (float*)d_out, N);
}

// Round 8
// 875.192 us; speedup vs baseline: 19.7135x; 1.3875x over previous
//
#include <hip/hip_runtime.h>
#include <hip/hip_bf16.h>

#define HIDF 128
#define OUTF 64
#define SCAN_B 256   // blocks in hierarchical scan

__device__ __forceinline__ float us2f(unsigned u_lo16) {           // bf16 bits in low 16
    return __uint_as_float(u_lo16 << 16);
}
__device__ __forceinline__ unsigned short f2us(float f) {          // RNE f32 -> bf16 bits
    __hip_bfloat16 h = __float2bfloat16(f);
    return *reinterpret_cast<unsigned short*>(&h);
}

// ---------------- degree / CSR build ----------------
__global__ __launch_bounds__(256) void deg_zero(int* __restrict__ d, int N) {
    int i = blockIdx.x * 256 + threadIdx.x;
    if (i < N) d[i] = 0;
}

__global__ __launch_bounds__(256) void deg_count(const int* __restrict__ ei, int* __restrict__ d, int E) {
    int e = blockIdx.x * 256 + threadIdx.x;
    if (e < E) atomicAdd(&d[ei[E + e]], 1);
}

__global__ __launch_bounds__(256) void scanA(const int* __restrict__ degi, int* __restrict__ blocksum, int N) {
    __shared__ int red[256];
    const int b = blockIdx.x;
    const int chunk = (N + SCAN_B - 1) / SCAN_B;
    const int lo = b * chunk, hi = min(lo + chunk, N);
    int s = 0;
    for (int i = lo + threadIdx.x; i < hi; i += 256) s += degi[i];
    red[threadIdx.x] = s;
    __syncthreads();
    for (int off = 128; off; off >>= 1) {
        if (threadIdx.x < off) red[threadIdx.x] += red[threadIdx.x + off];
        __syncthreads();
    }
    if (threadIdx.x == 0) blocksum[b] = red[0];
}

__global__ __launch_bounds__(256) void scanB(const int* __restrict__ blocksum, int* __restrict__ blockoff) {
    __shared__ int ps[256];
    const int t = threadIdx.x;
    ps[t] = blocksum[t];
    __syncthreads();
    for (int off = 1; off < 256; off <<= 1) {
        int v = ps[t];
        int u = (t >= off) ? ps[t - off] : 0;
        __syncthreads();
        ps[t] = v + u;
        __syncthreads();
    }
    blockoff[t] = (t == 0) ? 0 : ps[t - 1];
}

__global__ __launch_bounds__(256) void scanC(const int* __restrict__ degi,
                                             const int* __restrict__ blockoff,
                                             int* __restrict__ cursor,
                                             float* __restrict__ dinv, int N) {
    __shared__ int ps[256];
    const int b = blockIdx.x;
    const int chunk = (N + SCAN_B - 1) / SCAN_B;
    const int lo = b * chunk, hi = min(lo + chunk, N);
    const int tchunk = (chunk + 255) / 256;
    const int tlo = lo + threadIdx.x * tchunk;
    const int thi = min(tlo + tchunk, hi);
    int s = 0;
    for (int i = tlo; i < thi; ++i) s += degi[i];
    ps[threadIdx.x] = s;
    __syncthreads();
    for (int off = 1; off < 256; off <<= 1) {
        int v = ps[threadIdx.x];
        int u = (threadIdx.x >= off) ? ps[threadIdx.x - off] : 0;
        __syncthreads();
        ps[threadIdx.x] = v + u;
        __syncthreads();
    }
    int base = blockoff[b] + ((threadIdx.x == 0) ? 0 : ps[threadIdx.x - 1]);
    for (int i = tlo; i < thi; ++i) {
        int d = degi[i];
        cursor[i] = base;
        base += d;
        dinv[i] = rsqrtf((float)d + 1.f);
    }
}

__global__ __launch_bounds__(256) void scatter_kernel(const int* __restrict__ ei,
                                                      int* __restrict__ cursor,
                                                      int* __restrict__ csr_src, int E) {
    int e = blockIdx.x * 256 + threadIdx.x;
    if (e >= E) return;
    int pos = atomicAdd(&cursor[ei[E + e]], 1);
    csr_src[pos] = ei[e];
}

// ---------------- convert: TB[n,:] = bf16( x[n,:] * dinv[n] ) ----------------
__global__ __launch_bounds__(256) void cvt_scale(const float* __restrict__ X,
                                                 const float* __restrict__ dinv,
                                                 unsigned short* __restrict__ TB, int N) {
    int g = blockIdx.x * 256 + threadIdx.x;   // float4-group index
    if (g >= N * 32) return;
    int n = g >> 5;
    float dv = dinv[n];
    float4 v = ((const float4*)X)[g];
    ushort4 o;
    o.x = f2us(v.x * dv); o.y = f2us(v.y * dv);
    o.z = f2us(v.z * dv); o.w = f2us(v.w * dv);
    ((ushort4*)TB)[g] = o;
}

// ---------------- CSR aggregation over bf16 rows (rows pre-scaled by dinv[src]):
// O[n,:] = dinv[n] * ( sum_src TB[src,:] + TB[n,:] )   fp32 accumulate, fp32 out
// 8/4-deep unroll for memory-level parallelism (latency-bound gather).
__global__ __launch_bounds__(256) void agg_b(const unsigned short* __restrict__ TB,
                                             const float* __restrict__ dinv,
                                             const int* __restrict__ csr_src,
                                             const int* __restrict__ rend,
                                             float* __restrict__ O, int N) {
    const int n = (blockIdx.x * 256 + threadIdx.x) >> 6;
    const int lane = threadIdx.x & 63;
    if (n >= N) return;
    const int start = (n == 0) ? 0 : rend[n - 1];
    const int end   = rend[n];
    const unsigned* Tv = (const unsigned*)TB;   // row = 64 uints (2 bf16 each)

    float ax0 = 0.f, ay0 = 0.f, ax1 = 0.f, ay1 = 0.f;
    int e = start;
    for (; e + 8 <= end; e += 8) {
        int s0 = csr_src[e + 0], s1 = csr_src[e + 1], s2 = csr_src[e + 2], s3 = csr_src[e + 3];
        int s4 = csr_src[e + 4], s5 = csr_src[e + 5], s6 = csr_src[e + 6], s7 = csr_src[e + 7];
        unsigned v0 = Tv[(size_t)s0 * 64 + lane];
        unsigned v1 = Tv[(size_t)s1 * 64 + lane];
        unsigned v2 = Tv[(size_t)s2 * 64 + lane];
        unsigned v3 = Tv[(size_t)s3 * 64 + lane];
        unsigned v4 = Tv[(size_t)s4 * 64 + lane];
        unsigned v5 = Tv[(size_t)s5 * 64 + lane];
        unsigned v6 = Tv[(size_t)s6 * 64 + lane];
        unsigned v7 = Tv[(size_t)s7 * 64 + lane];
        ax0 += us2f(v0 & 0xffffu); ay0 += __uint_as_float(v0 & 0xffff0000u);
        ax1 += us2f(v1 & 0xffffu); ay1 += __uint_as_float(v1 & 0xffff0000u);
        ax0 += us2f(v2 & 0xffffu); ay0 += __uint_as_float(v2 & 0xffff0000u);
        ax1 += us2f(v3 & 0xffffu); ay1 += __uint_as_float(v3 & 0xffff0000u);
        ax0 += us2f(v4 & 0xffffu); ay0 += __uint_as_float(v4 & 0xffff0000u);
        ax1 += us2f(v5 & 0xffffu); ay1 += __uint_as_float(v5 & 0xffff0000u);
        ax0 += us2f(v6 & 0xffffu); ay0 += __uint_as_float(v6 & 0xffff0000u);
        ax1 += us2f(v7 & 0xffffu); ay1 += __uint_as_float(v7 & 0xffff0000u);
    }
    if (e + 4 <= end) {
        int s0 = csr_src[e + 0], s1 = csr_src[e + 1], s2 = csr_src[e + 2], s3 = csr_src[e + 3];
        unsigned v0 = Tv[(size_t)s0 * 64 + lane];
        unsigned v1 = Tv[(size_t)s1 * 64 + lane];
        unsigned v2 = Tv[(size_t)s2 * 64 + lane];
        unsigned v3 = Tv[(size_t)s3 * 64 + lane];
        ax0 += us2f(v0 & 0xffffu); ay0 += __uint_as_float(v0 & 0xffff0000u);
        ax1 += us2f(v1 & 0xffffu); ay1 += __uint_as_float(v1 & 0xffff0000u);
        ax0 += us2f(v2 & 0xffffu); ay0 += __uint_as_float(v2 & 0xffff0000u);
        ax1 += us2f(v3 & 0xffffu); ay1 += __uint_as_float(v3 & 0xffff0000u);
        e += 4;
    }
    for (; e < end; ++e) {
        int s = csr_src[e];
        unsigned v = Tv[(size_t)s * 64 + lane];
        ax0 += us2f(v & 0xffffu);
        ay0 += __uint_as_float(v & 0xffff0000u);
    }
    unsigned sv = Tv[(size_t)n * 64 + lane];
    ax0 += us2f(sv & 0xffffu);
    ay0 += __uint_as_float(sv & 0xffff0000u);
    const float dv = dinv[n];
    float2 o;
    o.x = (ax0 + ax1) * dv;
    o.y = (ay0 + ay1) * dv;
    ((float2*)O)[(size_t)n * 64 + lane] = o;
}

// ---------------- GEMM: out = X @ W + b, with selectable epilogue/output ----------------
#define OM_F32 0
#define OM_BF16 1
#define OM_BF16_SR 2
template <int OMODE>
__global__ __launch_bounds__(256) void gemm128d(const float* __restrict__ X,
                                                const float* __restrict__ W,
                                                const float* __restrict__ bias,
                                                const float* __restrict__ dinv,
                                                void* __restrict__ T, int N) {
    __shared__ float Xs[HIDF][68];   // transposed tile, padded
    const int tid = threadIdx.x;
    const int nb = blockIdx.x * 64;

    {   // load tile: node nloc = tid&63; 4 threads/node cover 32 float4-quads
        const int nloc = tid & 63;
        const int n = nb + nloc;
        const int kq0 = tid >> 6;   // 0..3
        if (n < N) {
            const float4* Xr = (const float4*)(X + (size_t)n * HIDF);
            #pragma unroll
            for (int kq = kq0; kq < 32; kq += 4) {
                float4 v = Xr[kq];
                int k = kq * 4;
                Xs[k + 0][nloc] = v.x;
                Xs[k + 1][nloc] = v.y;
                Xs[k + 2][nloc] = v.z;
                Xs[k + 3][nloc] = v.w;
            }
        } else {
            #pragma unroll
            for (int kq = kq0; kq < 32; kq += 4) {
                int k = kq * 4;
                Xs[k + 0][nloc] = 0.f; Xs[k + 1][nloc] = 0.f;
                Xs[k + 2][nloc] = 0.f; Xs[k + 3][nloc] = 0.f;
            }
        }
    }
    __syncthreads();

    const int j4  = tid & 31;   // 4-column group
    const int sub = tid >> 5;   // owns nodes sub*8 .. sub*8+7
    const float4* Wrow = (const float4*)W;
    const float4 bv = ((const float4*)bias)[j4];

    float4 acc[8];
    #pragma unroll
    for (int i = 0; i < 8; ++i) acc[i] = bv;

    #pragma unroll 4
    for (int k = 0; k < HIDF; ++k) {
        float4 w = Wrow[k * 32 + j4];
        float xv[8];
        *(float4*)&xv[0] = *(const float4*)&Xs[k][sub * 8];
        *(float4*)&xv[4] = *(const float4*)&Xs[k][sub * 8 + 4];
        #pragma unroll
        for (int i = 0; i < 8; ++i) {
            acc[i].x = fmaf(xv[i], w.x, acc[i].x);
            acc[i].y = fmaf(xv[i], w.y, acc[i].y);
            acc[i].z = fmaf(xv[i], w.z, acc[i].z);
            acc[i].w = fmaf(xv[i], w.w, acc[i].w);
        }
    }

    #pragma unroll
    for (int i = 0; i < 8; ++i) {
        int n = nb + sub * 8 + i;
        if (n >= N) continue;
        float4 o = acc[i];
        if (OMODE == OM_BF16_SR) {
            float dv = dinv[n];
            o.x = fmaxf(o.x, 0.f) * dv; o.y = fmaxf(o.y, 0.f) * dv;
            o.z = fmaxf(o.z, 0.f) * dv; o.w = fmaxf(o.w, 0.f) * dv;
        }
        if (OMODE == OM_F32) {
            *((float4*)((float*)T + (size_t)n * HIDF + j4 * 4)) = o;
        } else {
            ushort4 u;
            u.x = f2us(o.x); u.y = f2us(o.y); u.z = f2us(o.z); u.w = f2us(o.w);
            *((ushort4*)((unsigned short*)T + (size_t)n * HIDF + j4 * 4)) = u;
        }
    }
}

// ---------------- meta: scores -> softmax -> weighted sum + h1 residual -> @Wf + bf ----------------
__global__ __launch_bounds__(256) void meta_kernel(const float* __restrict__ H1,
                                                   const unsigned short* __restrict__ H2B,
                                                   const unsigned short* __restrict__ H3B,
                                                   const float* __restrict__ Wa,
                                                   const float* __restrict__ ba,
                                                   const float* __restrict__ Wf,
                                                   const float* __restrict__ bfb,
                                                   float* __restrict__ out, int N) {
    __shared__ float WfS[HIDF * OUTF];  // 32 KB
    __shared__ float WaS[HIDF];
    __shared__ float hm[4][HIDF];
    const int tid = threadIdx.x;
    for (int i = tid; i < HIDF * OUTF; i += 256) WfS[i] = Wf[i];
    if (tid < HIDF) WaS[tid] = Wa[tid];
    __syncthreads();
    const float bav = ba[0];
    const int w = tid >> 6;   // node within group of 4
    const int l = tid & 63;   // lane
    const float bfv = bfb[l];
    const int iters = (N + 3) >> 2;

    for (int it = blockIdx.x; it < iters; it += gridDim.x) {
        const int n = it * 4 + w;
        __syncthreads();  // protect hm from previous iteration's readers
        if (n < N) {
            const float* h1 = H1 + (size_t)n * HIDF;
            const unsigned short* h2 = H2B + (size_t)n * HIDF;
            const unsigned short* h3 = H3B + (size_t)n * HIDF;
            float h1a = fmaxf(h1[l], 0.f),            h1b = fmaxf(h1[l + 64], 0.f);
            float h2a = fmaxf(us2f(h2[l]), 0.f),      h2b = fmaxf(us2f(h2[l + 64]), 0.f);
            float h3a = fmaxf(us2f(h3[l]), 0.f),      h3b = fmaxf(us2f(h3[l + 64]), 0.f);
            float s1 = h1a * WaS[l] + h1b * WaS[l + 64];
            float s2 = h2a * WaS[l] + h2b * WaS[l + 64];
            float s3 = h3a * WaS[l] + h3b * WaS[l + 64];
            #pragma unroll
            for (int off = 32; off; off >>= 1) {
                s1 += __shfl_xor(s1, off);
                s2 += __shfl_xor(s2, off);
                s3 += __shfl_xor(s3, off);
            }
            s1 += bav; s2 += bav; s3 += bav;
            float m  = fmaxf(s1, fmaxf(s2, s3));
            float e1 = expf(s1 - m), e2 = expf(s2 - m), e3 = expf(s3 - m);
            float inv = 1.f / (e1 + e2 + e3);
            float w1 = e1 * inv, w2 = e2 * inv, w3 = e3 * inv;
            hm[w][l]      = w1 * h1a + w2 * h2a + w3 * h3a + h1a;
            hm[w][l + 64] = w1 * h1b + w2 * h2b + w3 * h3b + h1b;
        }
        __syncthreads();
        if (n < N) {
            float acc = bfv;
            #pragma unroll
            for (int k = 0; k < HIDF; ++k) acc = fmaf(hm[w][k], WfS[k * OUTF + l], acc);
            out[(size_t)n * OUTF + l] = acc;
        }
    }
}

// ---------------- launch ----------------
extern "C" void kernel_launch(void* const* d_in, const int* in_sizes, int n_in,
                              void* d_out, int out_size, void* d_ws, size_t ws_size,
                              hipStream_t stream) {
    const float* x   = (const float*)d_in[0];
    const int*   ei  = (const int*)d_in[1];
    const float *W1  = (const float*)d_in[2],  *b1  = (const float*)d_in[3];
    const float *W21 = (const float*)d_in[4],  *b21 = (const float*)d_in[5];
    const float *W22 = (const float*)d_in[6],  *b22 = (const float*)d_in[7];
    const float *W31 = (const float*)d_in[8],  *b31 = (const float*)d_in[9];
    const float *W32 = (const float*)d_in[10], *b32 = (const float*)d_in[11];
    const float *W33 = (const float*)d_in[12], *b33 = (const float*)d_in[13];
    const float *Wa  = (const float*)d_in[14], *ba  = (const float*)d_in[15];
    const float *Wf  = (const float*)d_in[16], *bfb = (const float*)d_in[17];

    const int N = in_sizes[0] / HIDF;
    const int E = in_sizes[1] / 2;

    // workspace: ints | DINV | TB(bf16) | PX(f32) | AG(f32) | H2B(bf16) | H3B(bf16)
    int*   DEGI    = (int*)d_ws;                          // N
    int*   CURSOR  = DEGI + N;                            // N
    int*   CSR_SRC = CURSOR + N;                          // E
    int*   BSUM    = CSR_SRC + E;                         // 256
    int*   BOFF    = BSUM + 256;                          // 256
    float* DINV    = (float*)(BOFF + 256);                // N
    unsigned short* TB = (unsigned short*)(DINV + N);     // N*128 bf16
    float* PX      = (float*)(TB + (size_t)N * HIDF);     // N*128 f32 (becomes H1 in-place)
    float* AG      = PX + (size_t)N * HIDF;               // N*128 f32 (agg scratch)
    unsigned short* H2B = (unsigned short*)(AG + (size_t)N * HIDF);  // N*128 bf16
    unsigned short* H3B = H2B + (size_t)N * HIDF;                    // N*128 bf16

    const int gN    = (N + 255) / 256;
    const int gE    = (E + 255) / 256;
    const int gCVT  = (N * 32 + 255) / 256;
    const int gAGG  = (N * 64 + 255) / 256;         // one wave per node
    const int gGEMM = (N + 63) / 64;
    const int gMETA = 2048;

    // CSR build
    deg_zero<<<gN, 256, 0, stream>>>(DEGI, N);
    deg_count<<<gE, 256, 0, stream>>>(ei, DEGI, E);
    scanA<<<SCAN_B, 256, 0, stream>>>(DEGI, BSUM, N);
    scanB<<<1, 256, 0, stream>>>(BSUM, BOFF);
    scanC<<<SCAN_B, 256, 0, stream>>>(DEGI, BOFF, CURSOR, DINV, N);
    scatter_kernel<<<gE, 256, 0, stream>>>(ei, CURSOR, CSR_SRC, E);

    // TB = bf16(x * dinv); PX = P x  (shared by all three branches)
    cvt_scale<<<gCVT, 256, 0, stream>>>(x, DINV, TB, N);
    agg_b<<<gAGG, 256, 0, stream>>>(TB, DINV, CSR_SRC, CURSOR, PX, N);

    // h2 chain: TB = bf16(relu(PX@W21+b21)*dinv) ; AG = P TB ; H2B = bf16(AG@W22+b22)
    gemm128d<OM_BF16_SR><<<gGEMM, 256, 0, stream>>>(PX, W21, b21, DINV, TB, N);
    agg_b<<<gAGG, 256, 0, stream>>>(TB, DINV, CSR_SRC, CURSOR, AG, N);
    gemm128d<OM_BF16><<<gGEMM, 256, 0, stream>>>(AG, W22, b22, DINV, H2B, N);

    // h3 chain
    gemm128d<OM_BF16_SR><<<gGEMM, 256, 0, stream>>>(PX, W31, b31, DINV, TB, N);
    agg_b<<<gAGG, 256, 0, stream>>>(TB, DINV, CSR_SRC, CURSOR, AG, N);
    gemm128d<OM_BF16_SR><<<gGEMM, 256, 0, stream>>>(AG, W32, b32, DINV, TB, N);
    agg_b<<<gAGG, 256, 0, stream>>>(TB, DINV, CSR_SRC, CURSOR, AG, N);
    gemm128d<OM_BF16><<<gGEMM, 256, 0, stream>>>(AG, W33, b33, DINV, H3B, N);

    // h1: PX <- PX@W1+b1   (in-place: per-block tile fully read into LDS before stores)
    gemm128d<OM_F32><<<gGEMM, 256, 0, stream>>>(PX, W1, b1, DINV, PX, N);

    // meta combine + final projection
    meta_kernel<<<gMETA, 256, 0, stream>>>(PX, H2B, H3B, Wa, ba, Wf, bfb,
                                           (float*)d_out, N);
}

// Round 9
// 853.586 us; speedup vs baseline: 20.2125x; 1.0253x over previous
//
#include <hip/hip_runtime.h>
#include <hip/hip_bf16.h>

#define HIDF 128
#define OUTF 64
#define SCAN_B 256   // blocks in hierarchical scan

__device__ __forceinline__ float us2f(unsigned u_lo16) {           // bf16 bits in low 16
    return __uint_as_float(u_lo16 << 16);
}
__device__ __forceinline__ unsigned short f2us(float f) {          // RNE f32 -> bf16 bits
    __hip_bfloat16 h = __float2bfloat16(f);
    return *reinterpret_cast<unsigned short*>(&h);
}
__device__ __forceinline__ unsigned pack2(float a, float b) {      // [lo=a, hi=b]
    return (unsigned)f2us(a) | ((unsigned)f2us(b) << 16);
}

// ---------------- degree / CSR build ----------------
__global__ __launch_bounds__(256) void deg_zero(int* __restrict__ d, int N) {
    int i = blockIdx.x * 256 + threadIdx.x;
    if (i < N) d[i] = 0;
}

__global__ __launch_bounds__(256) void deg_count(const int* __restrict__ ei, int* __restrict__ d, int E) {
    int e = blockIdx.x * 256 + threadIdx.x;
    if (e < E) atomicAdd(&d[ei[E + e]], 1);
}

__global__ __launch_bounds__(256) void scanA(const int* __restrict__ degi, int* __restrict__ blocksum, int N) {
    __shared__ int red[256];
    const int b = blockIdx.x;
    const int chunk = (N + SCAN_B - 1) / SCAN_B;
    const int lo = b * chunk, hi = min(lo + chunk, N);
    int s = 0;
    for (int i = lo + threadIdx.x; i < hi; i += 256) s += degi[i];
    red[threadIdx.x] = s;
    __syncthreads();
    for (int off = 128; off; off >>= 1) {
        if (threadIdx.x < off) red[threadIdx.x] += red[threadIdx.x + off];
        __syncthreads();
    }
    if (threadIdx.x == 0) blocksum[b] = red[0];
}

__global__ __launch_bounds__(256) void scanB(const int* __restrict__ blocksum, int* __restrict__ blockoff) {
    __shared__ int ps[256];
    const int t = threadIdx.x;
    ps[t] = blocksum[t];
    __syncthreads();
    for (int off = 1; off < 256; off <<= 1) {
        int v = ps[t];
        int u = (t >= off) ? ps[t - off] : 0;
        __syncthreads();
        ps[t] = v + u;
        __syncthreads();
    }
    blockoff[t] = (t == 0) ? 0 : ps[t - 1];
}

__global__ __launch_bounds__(256) void scanC(const int* __restrict__ degi,
                                             const int* __restrict__ blockoff,
                                             int* __restrict__ cursor,
                                             float* __restrict__ dinv, int N) {
    __shared__ int ps[256];
    const int b = blockIdx.x;
    const int chunk = (N + SCAN_B - 1) / SCAN_B;
    const int lo = b * chunk, hi = min(lo + chunk, N);
    const int tchunk = (chunk + 255) / 256;
    const int tlo = lo + threadIdx.x * tchunk;
    const int thi = min(tlo + tchunk, hi);
    int s = 0;
    for (int i = tlo; i < thi; ++i) s += degi[i];
    ps[threadIdx.x] = s;
    __syncthreads();
    for (int off = 1; off < 256; off <<= 1) {
        int v = ps[threadIdx.x];
        int u = (threadIdx.x >= off) ? ps[threadIdx.x - off] : 0;
        __syncthreads();
        ps[threadIdx.x] = v + u;
        __syncthreads();
    }
    int base = blockoff[b] + ((threadIdx.x == 0) ? 0 : ps[threadIdx.x - 1]);
    for (int i = tlo; i < thi; ++i) {
        int d = degi[i];
        cursor[i] = base;
        base += d;
        dinv[i] = rsqrtf((float)d + 1.f);
    }
}

__global__ __launch_bounds__(256) void scatter_kernel(const int* __restrict__ ei,
                                                      int* __restrict__ cursor,
                                                      int* __restrict__ csr_src, int E) {
    int e = blockIdx.x * 256 + threadIdx.x;
    if (e >= E) return;
    int pos = atomicAdd(&cursor[ei[E + e]], 1);
    csr_src[pos] = ei[e];
}

// ---------------- convert: TB[n,:] = bf16( x[n,:] * dinv[n] ) ----------------
__global__ __launch_bounds__(256) void cvt_scale(const float* __restrict__ X,
                                                 const float* __restrict__ dinv,
                                                 unsigned short* __restrict__ TB, int N) {
    int g = blockIdx.x * 256 + threadIdx.x;   // float4-group index
    if (g >= N * 32) return;
    int n = g >> 5;
    float dv = dinv[n];
    float4 v = ((const float4*)X)[g];
    ushort4 o;
    o.x = f2us(v.x * dv); o.y = f2us(v.y * dv);
    o.z = f2us(v.z * dv); o.w = f2us(v.w * dv);
    ((ushort4*)TB)[g] = o;
}

// ---------------- single CSR aggregation over bf16 rows (pre-scaled by dinv[src]):
// O[n,:] = dinv[n] * ( sum_src TB[src,:] + TB[n,:] ), fp32 accumulate; out f32 or bf16
template <bool OUT_BF16>
__global__ __launch_bounds__(256) void agg_b(const unsigned short* __restrict__ TB,
                                             const float* __restrict__ dinv,
                                             const int* __restrict__ csr_src,
                                             const int* __restrict__ rend,
                                             void* __restrict__ O, int N) {
    const int n = (blockIdx.x * 256 + threadIdx.x) >> 6;
    const int lane = threadIdx.x & 63;
    if (n >= N) return;
    const int start = (n == 0) ? 0 : rend[n - 1];
    const int end   = rend[n];
    const unsigned* Tv = (const unsigned*)TB;   // row = 64 uints (2 bf16 each)

    float ax0 = 0.f, ay0 = 0.f, ax1 = 0.f, ay1 = 0.f;
    int e = start;
    for (; e + 8 <= end; e += 8) {
        int s0 = csr_src[e + 0], s1 = csr_src[e + 1], s2 = csr_src[e + 2], s3 = csr_src[e + 3];
        int s4 = csr_src[e + 4], s5 = csr_src[e + 5], s6 = csr_src[e + 6], s7 = csr_src[e + 7];
        unsigned v0 = Tv[(size_t)s0 * 64 + lane];
        unsigned v1 = Tv[(size_t)s1 * 64 + lane];
        unsigned v2 = Tv[(size_t)s2 * 64 + lane];
        unsigned v3 = Tv[(size_t)s3 * 64 + lane];
        unsigned v4 = Tv[(size_t)s4 * 64 + lane];
        unsigned v5 = Tv[(size_t)s5 * 64 + lane];
        unsigned v6 = Tv[(size_t)s6 * 64 + lane];
        unsigned v7 = Tv[(size_t)s7 * 64 + lane];
        ax0 += us2f(v0 & 0xffffu); ay0 += __uint_as_float(v0 & 0xffff0000u);
        ax1 += us2f(v1 & 0xffffu); ay1 += __uint_as_float(v1 & 0xffff0000u);
        ax0 += us2f(v2 & 0xffffu); ay0 += __uint_as_float(v2 & 0xffff0000u);
        ax1 += us2f(v3 & 0xffffu); ay1 += __uint_as_float(v3 & 0xffff0000u);
        ax0 += us2f(v4 & 0xffffu); ay0 += __uint_as_float(v4 & 0xffff0000u);
        ax1 += us2f(v5 & 0xffffu); ay1 += __uint_as_float(v5 & 0xffff0000u);
        ax0 += us2f(v6 & 0xffffu); ay0 += __uint_as_float(v6 & 0xffff0000u);
        ax1 += us2f(v7 & 0xffffu); ay1 += __uint_as_float(v7 & 0xffff0000u);
    }
    if (e + 4 <= end) {
        int s0 = csr_src[e + 0], s1 = csr_src[e + 1], s2 = csr_src[e + 2], s3 = csr_src[e + 3];
        unsigned v0 = Tv[(size_t)s0 * 64 + lane];
        unsigned v1 = Tv[(size_t)s1 * 64 + lane];
        unsigned v2 = Tv[(size_t)s2 * 64 + lane];
        unsigned v3 = Tv[(size_t)s3 * 64 + lane];
        ax0 += us2f(v0 & 0xffffu); ay0 += __uint_as_float(v0 & 0xffff0000u);
        ax1 += us2f(v1 & 0xffffu); ay1 += __uint_as_float(v1 & 0xffff0000u);
        ax0 += us2f(v2 & 0xffffu); ay0 += __uint_as_float(v2 & 0xffff0000u);
        ax1 += us2f(v3 & 0xffffu); ay1 += __uint_as_float(v3 & 0xffff0000u);
        e += 4;
    }
    for (; e < end; ++e) {
        int s = csr_src[e];
        unsigned v = Tv[(size_t)s * 64 + lane];
        ax0 += us2f(v & 0xffffu);
        ay0 += __uint_as_float(v & 0xffff0000u);
    }
    unsigned sv = Tv[(size_t)n * 64 + lane];
    ax0 += us2f(sv & 0xffffu);
    ay0 += __uint_as_float(sv & 0xffff0000u);
    const float dv = dinv[n];
    float ox = (ax0 + ax1) * dv;
    float oy = (ay0 + ay1) * dv;
    if (OUT_BF16) {
        ((unsigned*)O)[(size_t)n * 64 + lane] = pack2(ox, oy);
    } else {
        float2 o; o.x = ox; o.y = oy;
        ((float2*)O)[(size_t)n * 64 + lane] = o;
    }
}

// ---------------- dual CSR aggregation: TB23[n][2][128] bf16 interleaved rows.
// OA[n,:] = dinv[n]*(sum TB23[src][0] + TB23[n][0]) ; OB same with half 1. bf16 out.
__global__ __launch_bounds__(256) void agg_dual(const unsigned short* __restrict__ TB23,
                                                const float* __restrict__ dinv,
                                                const int* __restrict__ csr_src,
                                                const int* __restrict__ rend,
                                                unsigned* __restrict__ OA,
                                                unsigned* __restrict__ OB, int N) {
    const int n = (blockIdx.x * 256 + threadIdx.x) >> 6;
    const int lane = threadIdx.x & 63;
    if (n >= N) return;
    const int start = (n == 0) ? 0 : rend[n - 1];
    const int end   = rend[n];
    const unsigned* Tv = (const unsigned*)TB23;   // node row = 128 uints: [0..63]=g2, [64..127]=g3

    float ax2 = 0.f, ay2 = 0.f, bx2 = 0.f, by2 = 0.f;
    float ax3 = 0.f, ay3 = 0.f, bx3 = 0.f, by3 = 0.f;
    int e = start;
    for (; e + 4 <= end; e += 4) {
        int s0 = csr_src[e + 0], s1 = csr_src[e + 1], s2 = csr_src[e + 2], s3 = csr_src[e + 3];
        unsigned a0 = Tv[(size_t)s0 * 128 + lane];
        unsigned c0 = Tv[(size_t)s0 * 128 + 64 + lane];
        unsigned a1 = Tv[(size_t)s1 * 128 + lane];
        unsigned c1 = Tv[(size_t)s1 * 128 + 64 + lane];
        unsigned a2 = Tv[(size_t)s2 * 128 + lane];
        unsigned c2 = Tv[(size_t)s2 * 128 + 64 + lane];
        unsigned a3 = Tv[(size_t)s3 * 128 + lane];
        unsigned c3 = Tv[(size_t)s3 * 128 + 64 + lane];
        ax2 += us2f(a0 & 0xffffu); ay2 += __uint_as_float(a0 & 0xffff0000u);
        ax3 += us2f(c0 & 0xffffu); ay3 += __uint_as_float(c0 & 0xffff0000u);
        bx2 += us2f(a1 & 0xffffu); by2 += __uint_as_float(a1 & 0xffff0000u);
        bx3 += us2f(c1 & 0xffffu); by3 += __uint_as_float(c1 & 0xffff0000u);
        ax2 += us2f(a2 & 0xffffu); ay2 += __uint_as_float(a2 & 0xffff0000u);
        ax3 += us2f(c2 & 0xffffu); ay3 += __uint_as_float(c2 & 0xffff0000u);
        bx2 += us2f(a3 & 0xffffu); by2 += __uint_as_float(a3 & 0xffff0000u);
        bx3 += us2f(c3 & 0xffffu); by3 += __uint_as_float(c3 & 0xffff0000u);
    }
    for (; e < end; ++e) {
        int s = csr_src[e];
        unsigned a = Tv[(size_t)s * 128 + lane];
        unsigned c = Tv[(size_t)s * 128 + 64 + lane];
        ax2 += us2f(a & 0xffffu); ay2 += __uint_as_float(a & 0xffff0000u);
        ax3 += us2f(c & 0xffffu); ay3 += __uint_as_float(c & 0xffff0000u);
    }
    {   // self-loop
        unsigned a = Tv[(size_t)n * 128 + lane];
        unsigned c = Tv[(size_t)n * 128 + 64 + lane];
        ax2 += us2f(a & 0xffffu); ay2 += __uint_as_float(a & 0xffff0000u);
        ax3 += us2f(c & 0xffffu); ay3 += __uint_as_float(c & 0xffff0000u);
    }
    const float dv = dinv[n];
    OA[(size_t)n * 64 + lane] = pack2((ax2 + bx2) * dv, (ay2 + by2) * dv);
    OB[(size_t)n * 64 + lane] = pack2((ax3 + bx3) * dv, (ay3 + by3) * dv);
}

// ---------------- GEMM: out = X @ W + b, selectable input dtype & epilogue ----------------
#define IM_F32 0
#define IM_BF16 1
#define OM_F32 0
#define OM_BF16 1
#define OM_BF16_SR 2
template <int IMODE, int OMODE>
__global__ __launch_bounds__(256) void gemm128d(const void* __restrict__ Xv,
                                                const float* __restrict__ W,
                                                const float* __restrict__ bias,
                                                const float* __restrict__ dinv,
                                                void* __restrict__ T, int N) {
    __shared__ float Xs[HIDF][68];   // transposed tile, padded
    const int tid = threadIdx.x;
    const int nb = blockIdx.x * 64;

    {   // load tile: node nloc = tid&63; 4 threads/node cover 32 quads
        const int nloc = tid & 63;
        const int n = nb + nloc;
        const int kq0 = tid >> 6;   // 0..3
        if (n < N) {
            if (IMODE == IM_F32) {
                const float4* Xr = (const float4*)((const float*)Xv + (size_t)n * HIDF);
                #pragma unroll
                for (int kq = kq0; kq < 32; kq += 4) {
                    float4 v = Xr[kq];
                    int k = kq * 4;
                    Xs[k + 0][nloc] = v.x;
                    Xs[k + 1][nloc] = v.y;
                    Xs[k + 2][nloc] = v.z;
                    Xs[k + 3][nloc] = v.w;
                }
            } else {
                const ushort4* Xr = (const ushort4*)((const unsigned short*)Xv + (size_t)n * HIDF);
                #pragma unroll
                for (int kq = kq0; kq < 32; kq += 4) {
                    ushort4 v = Xr[kq];
                    int k = kq * 4;
                    Xs[k + 0][nloc] = us2f(v.x);
                    Xs[k + 1][nloc] = us2f(v.y);
                    Xs[k + 2][nloc] = us2f(v.z);
                    Xs[k + 3][nloc] = us2f(v.w);
                }
            }
        } else {
            #pragma unroll
            for (int kq = kq0; kq < 32; kq += 4) {
                int k = kq * 4;
                Xs[k + 0][nloc] = 0.f; Xs[k + 1][nloc] = 0.f;
                Xs[k + 2][nloc] = 0.f; Xs[k + 3][nloc] = 0.f;
            }
        }
    }
    __syncthreads();

    const int j4  = tid & 31;   // 4-column group
    const int sub = tid >> 5;   // owns nodes sub*8 .. sub*8+7
    const float4* Wrow = (const float4*)W;
    const float4 bv = ((const float4*)bias)[j4];

    float4 acc[8];
    #pragma unroll
    for (int i = 0; i < 8; ++i) acc[i] = bv;

    #pragma unroll 4
    for (int k = 0; k < HIDF; ++k) {
        float4 w = Wrow[k * 32 + j4];
        float xv[8];
        *(float4*)&xv[0] = *(const float4*)&Xs[k][sub * 8];
        *(float4*)&xv[4] = *(const float4*)&Xs[k][sub * 8 + 4];
        #pragma unroll
        for (int i = 0; i < 8; ++i) {
            acc[i].x = fmaf(xv[i], w.x, acc[i].x);
            acc[i].y = fmaf(xv[i], w.y, acc[i].y);
            acc[i].z = fmaf(xv[i], w.z, acc[i].z);
            acc[i].w = fmaf(xv[i], w.w, acc[i].w);
        }
    }

    #pragma unroll
    for (int i = 0; i < 8; ++i) {
        int n = nb + sub * 8 + i;
        if (n >= N) continue;
        float4 o = acc[i];
        if (OMODE == OM_BF16_SR) {
            float dv = dinv[n];
            o.x = fmaxf(o.x, 0.f) * dv; o.y = fmaxf(o.y, 0.f) * dv;
            o.z = fmaxf(o.z, 0.f) * dv; o.w = fmaxf(o.w, 0.f) * dv;
        }
        if (OMODE == OM_F32) {
            *((float4*)((float*)T + (size_t)n * HIDF + j4 * 4)) = o;
        } else {
            ushort4 u;
            u.x = f2us(o.x); u.y = f2us(o.y); u.z = f2us(o.z); u.w = f2us(o.w);
            *((ushort4*)((unsigned short*)T + (size_t)n * HIDF + j4 * 4)) = u;
        }
    }
}

// ---------------- dual GEMM: TB23[n][2][128] = { relu(X@W21+b21)*dinv, relu(X@W31+b31)*dinv } bf16
__global__ __launch_bounds__(256) void gemm_dualA(const float* __restrict__ X,
                                                  const float* __restrict__ W21,
                                                  const float* __restrict__ b21,
                                                  const float* __restrict__ W31,
                                                  const float* __restrict__ b31,
                                                  const float* __restrict__ dinv,
                                                  unsigned short* __restrict__ TB23, int N) {
    __shared__ float Xs[HIDF][68];
    const int tid = threadIdx.x;
    const int nb = blockIdx.x * 64;

    {
        const int nloc = tid & 63;
        const int n = nb + nloc;
        const int kq0 = tid >> 6;
        if (n < N) {
            const float4* Xr = (const float4*)(X + (size_t)n * HIDF);
            #pragma unroll
            for (int kq = kq0; kq < 32; kq += 4) {
                float4 v = Xr[kq];
                int k = kq * 4;
                Xs[k + 0][nloc] = v.x;
                Xs[k + 1][nloc] = v.y;
                Xs[k + 2][nloc] = v.z;
                Xs[k + 3][nloc] = v.w;
            }
        } else {
            #pragma unroll
            for (int kq = kq0; kq < 32; kq += 4) {
                int k = kq * 4;
                Xs[k + 0][nloc] = 0.f; Xs[k + 1][nloc] = 0.f;
                Xs[k + 2][nloc] = 0.f; Xs[k + 3][nloc] = 0.f;
            }
        }
    }
    __syncthreads();

    const int j4  = tid & 31;
    const int sub = tid >> 5;
    const float4* W2r = (const float4*)W21;
    const float4* W3r = (const float4*)W31;
    const float4 bv2 = ((const float4*)b21)[j4];
    const float4 bv3 = ((const float4*)b31)[j4];

    float4 acc2[8], acc3[8];
    #pragma unroll
    for (int i = 0; i < 8; ++i) { acc2[i] = bv2; acc3[i] = bv3; }

    #pragma unroll 2
    for (int k = 0; k < HIDF; ++k) {
        float4 w2 = W2r[k * 32 + j4];
        float4 w3 = W3r[k * 32 + j4];
        float xv[8];
        *(float4*)&xv[0] = *(const float4*)&Xs[k][sub * 8];
        *(float4*)&xv[4] = *(const float4*)&Xs[k][sub * 8 + 4];
        #pragma unroll
        for (int i = 0; i < 8; ++i) {
            acc2[i].x = fmaf(xv[i], w2.x, acc2[i].x);
            acc2[i].y = fmaf(xv[i], w2.y, acc2[i].y);
            acc2[i].z = fmaf(xv[i], w2.z, acc2[i].z);
            acc2[i].w = fmaf(xv[i], w2.w, acc2[i].w);
            acc3[i].x = fmaf(xv[i], w3.x, acc3[i].x);
            acc3[i].y = fmaf(xv[i], w3.y, acc3[i].y);
            acc3[i].z = fmaf(xv[i], w3.z, acc3[i].z);
            acc3[i].w = fmaf(xv[i], w3.w, acc3[i].w);
        }
    }

    #pragma unroll
    for (int i = 0; i < 8; ++i) {
        int n = nb + sub * 8 + i;
        if (n >= N) continue;
        float dv = dinv[n];
        float4 o2 = acc2[i], o3 = acc3[i];
        ushort4 u2, u3;
        u2.x = f2us(fmaxf(o2.x, 0.f) * dv); u2.y = f2us(fmaxf(o2.y, 0.f) * dv);
        u2.z = f2us(fmaxf(o2.z, 0.f) * dv); u2.w = f2us(fmaxf(o2.w, 0.f) * dv);
        u3.x = f2us(fmaxf(o3.x, 0.f) * dv); u3.y = f2us(fmaxf(o3.y, 0.f) * dv);
        u3.z = f2us(fmaxf(o3.z, 0.f) * dv); u3.w = f2us(fmaxf(o3.w, 0.f) * dv);
        unsigned short* base = TB23 + (size_t)n * 256;
        *((ushort4*)(base + j4 * 4)) = u2;
        *((ushort4*)(base + 128 + j4 * 4)) = u3;
    }
}

// ---------------- meta: scores -> softmax -> weighted sum + h1 residual -> @Wf + bf ----------------
__global__ __launch_bounds__(256) void meta_kernel(const float* __restrict__ H1,
                                                   const unsigned short* __restrict__ H2B,
                                                   const unsigned short* __restrict__ H3B,
                                                   const float* __restrict__ Wa,
                                                   const float* __restrict__ ba,
                                                   const float* __restrict__ Wf,
                                                   const float* __restrict__ bfb,
                                                   float* __restrict__ out, int N) {
    __shared__ float WfS[HIDF * OUTF];  // 32 KB
    __shared__ float WaS[HIDF];
    __shared__ float hm[4][HIDF];
    const int tid = threadIdx.x;
    for (int i = tid; i < HIDF * OUTF; i += 256) WfS[i] = Wf[i];
    if (tid < HIDF) WaS[tid] = Wa[tid];
    __syncthreads();
    const float bav = ba[0];
    const int w = tid >> 6;   // node within group of 4
    const int l = tid & 63;   // lane
    const float bfv = bfb[l];
    const int iters = (N + 3) >> 2;

    for (int it = blockIdx.x; it < iters; it += gridDim.x) {
        const int n = it * 4 + w;
        __syncthreads();  // protect hm from previous iteration's readers
        if (n < N) {
            const float* h1 = H1 + (size_t)n * HIDF;
            const unsigned short* h2 = H2B + (size_t)n * HIDF;
            const unsigned short* h3 = H3B + (size_t)n * HIDF;
            float h1a = fmaxf(h1[l], 0.f),            h1b = fmaxf(h1[l + 64], 0.f);
            float h2a = fmaxf(us2f(h2[l]), 0.f),      h2b = fmaxf(us2f(h2[l + 64]), 0.f);
            float h3a = fmaxf(us2f(h3[l]), 0.f),      h3b = fmaxf(us2f(h3[l + 64]), 0.f);
            float s1 = h1a * WaS[l] + h1b * WaS[l + 64];
            float s2 = h2a * WaS[l] + h2b * WaS[l + 64];
            float s3 = h3a * WaS[l] + h3b * WaS[l + 64];
            #pragma unroll
            for (int off = 32; off; off >>= 1) {
                s1 += __shfl_xor(s1, off);
                s2 += __shfl_xor(s2, off);
                s3 += __shfl_xor(s3, off);
            }
            s1 += bav; s2 += bav; s3 += bav;
            float m  = fmaxf(s1, fmaxf(s2, s3));
            float e1 = expf(s1 - m), e2 = expf(s2 - m), e3 = expf(s3 - m);
            float inv = 1.f / (e1 + e2 + e3);
            float w1 = e1 * inv, w2 = e2 * inv, w3 = e3 * inv;
            hm[w][l]      = w1 * h1a + w2 * h2a + w3 * h3a + h1a;
            hm[w][l + 64] = w1 * h1b + w2 * h2b + w3 * h3b + h1b;
        }
        __syncthreads();
        if (n < N) {
            float acc = bfv;
            #pragma unroll
            for (int k = 0; k < HIDF; ++k) acc = fmaf(hm[w][k], WfS[k * OUTF + l], acc);
            out[(size_t)n * OUTF + l] = acc;
        }
    }
}

// ---------------- launch ----------------
extern "C" void kernel_launch(void* const* d_in, const int* in_sizes, int n_in,
                              void* d_out, int out_size, void* d_ws, size_t ws_size,
                              hipStream_t stream) {
    const float* x   = (const float*)d_in[0];
    const int*   ei  = (const int*)d_in[1];
    const float *W1  = (const float*)d_in[2],  *b1  = (const float*)d_in[3];
    const float *W21 = (const float*)d_in[4],  *b21 = (const float*)d_in[5];
    const float *W22 = (const float*)d_in[6],  *b22 = (const float*)d_in[7];
    const float *W31 = (const float*)d_in[8],  *b31 = (const float*)d_in[9];
    const float *W32 = (const float*)d_in[10], *b32 = (const float*)d_in[11];
    const float *W33 = (const float*)d_in[12], *b33 = (const float*)d_in[13];
    const float *Wa  = (const float*)d_in[14], *ba  = (const float*)d_in[15];
    const float *Wf  = (const float*)d_in[16], *bfb = (const float*)d_in[17];

    const int N = in_sizes[0] / HIDF;
    const int E = in_sizes[1] / 2;

    // workspace: ints | DINV | TB23(bf16, 2 rows/node; also hosts plain TBX) |
    //            PX(f32, ->H1 in-place) | AGA(bf16) | AGB(bf16, ->H3B) | H2B(bf16)   (~187 MB)
    int*   DEGI    = (int*)d_ws;                          // N
    int*   CURSOR  = DEGI + N;                            // N
    int*   CSR_SRC = CURSOR + N;                          // E
    int*   BSUM    = CSR_SRC + E;                         // 256
    int*   BOFF    = BSUM + 256;                          // 256
    float* DINV    = (float*)(BOFF + 256);                // N
    unsigned short* TB23 = (unsigned short*)(DINV + N);   // N*256 bf16
    float* PX      = (float*)(TB23 + (size_t)N * 256);    // N*128 f32
    unsigned* AGA  = (unsigned*)(PX + (size_t)N * HIDF);  // N*64 uints (bf16 pairs)
    unsigned* AGB  = AGA + (size_t)N * 64;                // N*64 uints
    unsigned* H2B  = AGB + (size_t)N * 64;                // N*64 uints

    const int gN    = (N + 255) / 256;
    const int gE    = (E + 255) / 256;
    const int gCVT  = (N * 32 + 255) / 256;
    const int gAGG  = (N * 64 + 255) / 256;         // one wave per node
    const int gGEMM = (N + 63) / 64;
    const int gMETA = 2048;

    // CSR build
    deg_zero<<<gN, 256, 0, stream>>>(DEGI, N);
    deg_count<<<gE, 256, 0, stream>>>(ei, DEGI, E);
    scanA<<<SCAN_B, 256, 0, stream>>>(DEGI, BSUM, N);
    scanB<<<1, 256, 0, stream>>>(BSUM, BOFF);
    scanC<<<SCAN_B, 256, 0, stream>>>(DEGI, BOFF, CURSOR, DINV, N);
    scatter_kernel<<<gE, 256, 0, stream>>>(ei, CURSOR, CSR_SRC, E);

    unsigned short* TBX = TB23;   // plain [n][128] bf16 view, reused

    // TBX = bf16(x*dinv); PX = P x
    cvt_scale<<<gCVT, 256, 0, stream>>>(x, DINV, TBX, N);
    agg_b<false><<<gAGG, 256, 0, stream>>>(TBX, DINV, CSR_SRC, CURSOR, PX, N);

    // fused g2/g3 first layer: TB23 = {relu(PX@W21)*dinv, relu(PX@W31)*dinv}
    gemm_dualA<<<gGEMM, 256, 0, stream>>>(PX, W21, b21, W31, b31, DINV, TB23, N);
    // fused aggregation: AGA = P g2, AGB = P g3  (bf16)
    agg_dual<<<gAGG, 256, 0, stream>>>(TB23, DINV, CSR_SRC, CURSOR, AGA, AGB, N);

    // h2 finish: H2B = AGA@W22+b22
    gemm128d<IM_BF16, OM_BF16><<<gGEMM, 256, 0, stream>>>(AGA, W22, b22, DINV, H2B, N);
    // h3 second layer: TBX = relu(AGB@W32+b32)*dinv   (TB23 region free now)
    gemm128d<IM_BF16, OM_BF16_SR><<<gGEMM, 256, 0, stream>>>(AGB, W32, b32, DINV, TBX, N);
    // h3 aggregation: AGA = P TBX  (AGA free after W22 gemm)
    agg_b<true><<<gAGG, 256, 0, stream>>>(TBX, DINV, CSR_SRC, CURSOR, AGA, N);
    // h3 finish: H3B (=AGB) = AGA@W33+b33
    gemm128d<IM_BF16, OM_BF16><<<gGEMM, 256, 0, stream>>>(AGA, W33, b33, DINV, AGB, N);

    // h1: PX <- PX@W1+b1 (in-place)
    gemm128d<IM_F32, OM_F32><<<gGEMM, 256, 0, stream>>>(PX, W1, b1, DINV, PX, N);

    // meta combine + final projection
    meta_kernel<<<gMETA, 256, 0, stream>>>(PX, (const unsigned short*)H2B,
                                           (const unsigned short*)AGB, Wa, ba, Wf, bfb,
                                           (float*)d_out, N);
}

// Round 10
// 752.503 us; speedup vs baseline: 22.9276x; 1.1343x over previous
//
#include <hip/hip_runtime.h>
#include <hip/hip_bf16.h>

#define HIDF 128
#define OUTF 64
#define SCAN_B 256   // blocks in hierarchical scan

typedef __attribute__((ext_vector_type(8))) short bf16x8;
typedef __attribute__((ext_vector_type(4))) float f32x4;

__device__ __forceinline__ float us2f(unsigned u_lo16) {           // bf16 bits in low 16
    return __uint_as_float(u_lo16 << 16);
}
__device__ __forceinline__ unsigned short f2us(float f) {          // RNE f32 -> bf16 bits
    __hip_bfloat16 h = __float2bfloat16(f);
    return *reinterpret_cast<unsigned short*>(&h);
}
__device__ __forceinline__ unsigned pack2(float a, float b) {      // [lo=a, hi=b]
    return (unsigned)f2us(a) | ((unsigned)f2us(b) << 16);
}

// ---------------- degree / CSR build ----------------
__global__ __launch_bounds__(256) void deg_zero(int* __restrict__ d, int N) {
    int i = blockIdx.x * 256 + threadIdx.x;
    if (i < N) d[i] = 0;
}

__global__ __launch_bounds__(256) void deg_count(const int* __restrict__ ei, int* __restrict__ d, int E) {
    int e = blockIdx.x * 256 + threadIdx.x;
    if (e < E) atomicAdd(&d[ei[E + e]], 1);
}

__global__ __launch_bounds__(256) void scanA(const int* __restrict__ degi, int* __restrict__ blocksum, int N) {
    __shared__ int red[256];
    const int b = blockIdx.x;
    const int chunk = (N + SCAN_B - 1) / SCAN_B;
    const int lo = b * chunk, hi = min(lo + chunk, N);
    int s = 0;
    for (int i = lo + threadIdx.x; i < hi; i += 256) s += degi[i];
    red[threadIdx.x] = s;
    __syncthreads();
    for (int off = 128; off; off >>= 1) {
        if (threadIdx.x < off) red[threadIdx.x] += red[threadIdx.x + off];
        __syncthreads();
    }
    if (threadIdx.x == 0) blocksum[b] = red[0];
}

__global__ __launch_bounds__(256) void scanB(const int* __restrict__ blocksum, int* __restrict__ blockoff) {
    __shared__ int ps[256];
    const int t = threadIdx.x;
    ps[t] = blocksum[t];
    __syncthreads();
    for (int off = 1; off < 256; off <<= 1) {
        int v = ps[t];
        int u = (t >= off) ? ps[t - off] : 0;
        __syncthreads();
        ps[t] = v + u;
        __syncthreads();
    }
    blockoff[t] = (t == 0) ? 0 : ps[t - 1];
}

__global__ __launch_bounds__(256) void scanC(const int* __restrict__ degi,
                                             const int* __restrict__ blockoff,
                                             int* __restrict__ cursor,
                                             float* __restrict__ dinv, int N) {
    __shared__ int ps[256];
    const int b = blockIdx.x;
    const int chunk = (N + SCAN_B - 1) / SCAN_B;
    const int lo = b * chunk, hi = min(lo + chunk, N);
    const int tchunk = (chunk + 255) / 256;
    const int tlo = lo + threadIdx.x * tchunk;
    const int thi = min(tlo + tchunk, hi);
    int s = 0;
    for (int i = tlo; i < thi; ++i) s += degi[i];
    ps[threadIdx.x] = s;
    __syncthreads();
    for (int off = 1; off < 256; off <<= 1) {
        int v = ps[threadIdx.x];
        int u = (threadIdx.x >= off) ? ps[threadIdx.x - off] : 0;
        __syncthreads();
        ps[threadIdx.x] = v + u;
        __syncthreads();
    }
    int base = blockoff[b] + ((threadIdx.x == 0) ? 0 : ps[threadIdx.x - 1]);
    for (int i = tlo; i < thi; ++i) {
        int d = degi[i];
        cursor[i] = base;
        base += d;
        dinv[i] = rsqrtf((float)d + 1.f);
    }
}

__global__ __launch_bounds__(256) void scatter_kernel(const int* __restrict__ ei,
                                                      int* __restrict__ cursor,
                                                      int* __restrict__ csr_src, int E) {
    int e = blockIdx.x * 256 + threadIdx.x;
    if (e >= E) return;
    int pos = atomicAdd(&cursor[ei[E + e]], 1);
    csr_src[pos] = ei[e];
}

// ---------------- convert: TB[n,:] = bf16( x[n,:] * dinv[n] ) ----------------
__global__ __launch_bounds__(256) void cvt_scale(const float* __restrict__ X,
                                                 const float* __restrict__ dinv,
                                                 unsigned short* __restrict__ TB, int N) {
    int g = blockIdx.x * 256 + threadIdx.x;   // float4-group index
    if (g >= N * 32) return;
    int n = g >> 5;
    float dv = dinv[n];
    float4 v = ((const float4*)X)[g];
    ushort4 o;
    o.x = f2us(v.x * dv); o.y = f2us(v.y * dv);
    o.z = f2us(v.z * dv); o.w = f2us(v.w * dv);
    ((ushort4*)TB)[g] = o;
}

// ---------------- convert 5 weight matrices f32 [k][n] -> bf16 transposed [n][k] ----------------
__global__ __launch_bounds__(256) void cvt_w(const float* __restrict__ Wa0,
                                             const float* __restrict__ Wa1,
                                             const float* __restrict__ Wa2,
                                             const float* __restrict__ Wa3,
                                             const float* __restrict__ Wa4,
                                             unsigned short* __restrict__ WTB) {
    int t = blockIdx.x * 256 + threadIdx.x;
    if (t >= 5 * 16384) return;
    int m = t >> 14, local = t & 16383;
    int n = local >> 7, k = local & 127;
    const float* src = (m == 0) ? Wa0 : (m == 1) ? Wa1 : (m == 2) ? Wa2 : (m == 3) ? Wa3 : Wa4;
    WTB[t] = f2us(src[k * 128 + n]);
}

// ---------------- single CSR aggregation over bf16 rows (pre-scaled by dinv[src]):
// O[n,:] = dinv[n] * ( sum_src TB[src,:] + TB[n,:] ), fp32 accumulate; out f32 or bf16
template <bool OUT_BF16>
__global__ __launch_bounds__(256) void agg_b(const unsigned short* __restrict__ TB,
                                             const float* __restrict__ dinv,
                                             const int* __restrict__ csr_src,
                                             const int* __restrict__ rend,
                                             void* __restrict__ O, int N) {
    const int n = (blockIdx.x * 256 + threadIdx.x) >> 6;
    const int lane = threadIdx.x & 63;
    if (n >= N) return;
    const int start = (n == 0) ? 0 : rend[n - 1];
    const int end   = rend[n];
    const unsigned* Tv = (const unsigned*)TB;   // row = 64 uints (2 bf16 each)

    float ax0 = 0.f, ay0 = 0.f, ax1 = 0.f, ay1 = 0.f;
    int e = start;
    for (; e + 8 <= end; e += 8) {
        int s0 = csr_src[e + 0], s1 = csr_src[e + 1], s2 = csr_src[e + 2], s3 = csr_src[e + 3];
        int s4 = csr_src[e + 4], s5 = csr_src[e + 5], s6 = csr_src[e + 6], s7 = csr_src[e + 7];
        unsigned v0 = Tv[(size_t)s0 * 64 + lane];
        unsigned v1 = Tv[(size_t)s1 * 64 + lane];
        unsigned v2 = Tv[(size_t)s2 * 64 + lane];
        unsigned v3 = Tv[(size_t)s3 * 64 + lane];
        unsigned v4 = Tv[(size_t)s4 * 64 + lane];
        unsigned v5 = Tv[(size_t)s5 * 64 + lane];
        unsigned v6 = Tv[(size_t)s6 * 64 + lane];
        unsigned v7 = Tv[(size_t)s7 * 64 + lane];
        ax0 += us2f(v0 & 0xffffu); ay0 += __uint_as_float(v0 & 0xffff0000u);
        ax1 += us2f(v1 & 0xffffu); ay1 += __uint_as_float(v1 & 0xffff0000u);
        ax0 += us2f(v2 & 0xffffu); ay0 += __uint_as_float(v2 & 0xffff0000u);
        ax1 += us2f(v3 & 0xffffu); ay1 += __uint_as_float(v3 & 0xffff0000u);
        ax0 += us2f(v4 & 0xffffu); ay0 += __uint_as_float(v4 & 0xffff0000u);
        ax1 += us2f(v5 & 0xffffu); ay1 += __uint_as_float(v5 & 0xffff0000u);
        ax0 += us2f(v6 & 0xffffu); ay0 += __uint_as_float(v6 & 0xffff0000u);
        ax1 += us2f(v7 & 0xffffu); ay1 += __uint_as_float(v7 & 0xffff0000u);
    }
    if (e + 4 <= end) {
        int s0 = csr_src[e + 0], s1 = csr_src[e + 1], s2 = csr_src[e + 2], s3 = csr_src[e + 3];
        unsigned v0 = Tv[(size_t)s0 * 64 + lane];
        unsigned v1 = Tv[(size_t)s1 * 64 + lane];
        unsigned v2 = Tv[(size_t)s2 * 64 + lane];
        unsigned v3 = Tv[(size_t)s3 * 64 + lane];
        ax0 += us2f(v0 & 0xffffu); ay0 += __uint_as_float(v0 & 0xffff0000u);
        ax1 += us2f(v1 & 0xffffu); ay1 += __uint_as_float(v1 & 0xffff0000u);
        ax0 += us2f(v2 & 0xffffu); ay0 += __uint_as_float(v2 & 0xffff0000u);
        ax1 += us2f(v3 & 0xffffu); ay1 += __uint_as_float(v3 & 0xffff0000u);
        e += 4;
    }
    for (; e < end; ++e) {
        int s = csr_src[e];
        unsigned v = Tv[(size_t)s * 64 + lane];
        ax0 += us2f(v & 0xffffu);
        ay0 += __uint_as_float(v & 0xffff0000u);
    }
    unsigned sv = Tv[(size_t)n * 64 + lane];
    ax0 += us2f(sv & 0xffffu);
    ay0 += __uint_as_float(sv & 0xffff0000u);
    const float dv = dinv[n];
    float ox = (ax0 + ax1) * dv;
    float oy = (ay0 + ay1) * dv;
    if (OUT_BF16) {
        ((unsigned*)O)[(size_t)n * 64 + lane] = pack2(ox, oy);
    } else {
        float2 o; o.x = ox; o.y = oy;
        ((float2*)O)[(size_t)n * 64 + lane] = o;
    }
}

// ---------------- dual CSR aggregation: TB23[n][2][128] bf16 interleaved rows ----------------
__global__ __launch_bounds__(256) void agg_dual(const unsigned short* __restrict__ TB23,
                                                const float* __restrict__ dinv,
                                                const int* __restrict__ csr_src,
                                                const int* __restrict__ rend,
                                                unsigned* __restrict__ OA,
                                                unsigned* __restrict__ OB, int N) {
    const int n = (blockIdx.x * 256 + threadIdx.x) >> 6;
    const int lane = threadIdx.x & 63;
    if (n >= N) return;
    const int start = (n == 0) ? 0 : rend[n - 1];
    const int end   = rend[n];
    const unsigned* Tv = (const unsigned*)TB23;   // node row = 128 uints: [0..63]=g2, [64..127]=g3

    float ax2 = 0.f, ay2 = 0.f, bx2 = 0.f, by2 = 0.f;
    float ax3 = 0.f, ay3 = 0.f, bx3 = 0.f, by3 = 0.f;
    int e = start;
    for (; e + 4 <= end; e += 4) {
        int s0 = csr_src[e + 0], s1 = csr_src[e + 1], s2 = csr_src[e + 2], s3 = csr_src[e + 3];
        unsigned a0 = Tv[(size_t)s0 * 128 + lane];
        unsigned c0 = Tv[(size_t)s0 * 128 + 64 + lane];
        unsigned a1 = Tv[(size_t)s1 * 128 + lane];
        unsigned c1 = Tv[(size_t)s1 * 128 + 64 + lane];
        unsigned a2 = Tv[(size_t)s2 * 128 + lane];
        unsigned c2 = Tv[(size_t)s2 * 128 + 64 + lane];
        unsigned a3 = Tv[(size_t)s3 * 128 + lane];
        unsigned c3 = Tv[(size_t)s3 * 128 + 64 + lane];
        ax2 += us2f(a0 & 0xffffu); ay2 += __uint_as_float(a0 & 0xffff0000u);
        ax3 += us2f(c0 & 0xffffu); ay3 += __uint_as_float(c0 & 0xffff0000u);
        bx2 += us2f(a1 & 0xffffu); by2 += __uint_as_float(a1 & 0xffff0000u);
        bx3 += us2f(c1 & 0xffffu); by3 += __uint_as_float(c1 & 0xffff0000u);
        ax2 += us2f(a2 & 0xffffu); ay2 += __uint_as_float(a2 & 0xffff0000u);
        ax3 += us2f(c2 & 0xffffu); ay3 += __uint_as_float(c2 & 0xffff0000u);
        bx2 += us2f(a3 & 0xffffu); by2 += __uint_as_float(a3 & 0xffff0000u);
        bx3 += us2f(c3 & 0xffffu); by3 += __uint_as_float(c3 & 0xffff0000u);
    }
    for (; e < end; ++e) {
        int s = csr_src[e];
        unsigned a = Tv[(size_t)s * 128 + lane];
        unsigned c = Tv[(size_t)s * 128 + 64 + lane];
        ax2 += us2f(a & 0xffffu); ay2 += __uint_as_float(a & 0xffff0000u);
        ax3 += us2f(c & 0xffffu); ay3 += __uint_as_float(c & 0xffff0000u);
    }
    {   // self-loop
        unsigned a = Tv[(size_t)n * 128 + lane];
        unsigned c = Tv[(size_t)n * 128 + 64 + lane];
        ax2 += us2f(a & 0xffffu); ay2 += __uint_as_float(a & 0xffff0000u);
        ax3 += us2f(c & 0xffffu); ay3 += __uint_as_float(c & 0xffff0000u);
    }
    const float dv = dinv[n];
    OA[(size_t)n * 64 + lane] = pack2((ax2 + bx2) * dv, (ay2 + by2) * dv);
    OB[(size_t)n * 64 + lane] = pack2((ax3 + bx3) * dv, (ay3 + by3) * dv);
}

// ---------------- MFMA GEMM: T = X @ W + b (bf16 in via LDS, bf16 out) ----------------
// 64-node tile x 128 cols; 4 waves x (16 rows, 8 n-tiles, K=128 in 4 steps of 32).
// LDS: Xs 16KB + Ws 32KB, both XOR-swizzled (chunk ^= row&7) on write AND read.
#define OM_BF16 1
#define OM_BF16_SR 2
template <int OMODE, int OSTRIDE, bool INF32>
__global__ __launch_bounds__(256) void gemm_mfma(const void* __restrict__ Xv,
                                                 const unsigned short* __restrict__ WT,  // [n][k] bf16
                                                 const float* __restrict__ bias,
                                                 const float* __restrict__ dinv,
                                                 unsigned short* __restrict__ T, int N) {
    __shared__ unsigned short Xs[64 * 128];   // 16 KB
    __shared__ unsigned short Ws[128 * 128];  // 32 KB
    const int tid = threadIdx.x;
    const int nb = blockIdx.x * 64;

    // stage W transposed (2048 x 16B chunks), swizzled
    for (int c = tid; c < 2048; c += 256) {
        int n = c >> 4, kc = c & 15;
        ((uint4*)Ws)[(n << 4) | (kc ^ (n & 7))] = ((const uint4*)WT)[c];
    }
    // stage X (1024 x 16B bf16 chunks), swizzled; f32 input converts on the fly
    for (int c = tid; c < 1024; c += 256) {
        int nl = c >> 4, kc = c & 15;
        int n = nb + nl;
        uint4 v = make_uint4(0u, 0u, 0u, 0u);
        if (n < N) {
            if (INF32) {
                const float4* Xr = (const float4*)((const float*)Xv + (size_t)n * HIDF);
                float4 v0 = Xr[kc * 2], v1 = Xr[kc * 2 + 1];
                v.x = pack2(v0.x, v0.y); v.y = pack2(v0.z, v0.w);
                v.z = pack2(v1.x, v1.y); v.w = pack2(v1.z, v1.w);
            } else {
                v = ((const uint4*)((const unsigned short*)Xv + (size_t)n * HIDF))[kc];
            }
        }
        ((uint4*)Xs)[(nl << 4) | (kc ^ (nl & 7))] = v;
    }
    __syncthreads();

    const int wv   = tid >> 6;    // wave id: rows 16wv..16wv+15
    const int l    = tid & 63;
    const int row  = l & 15;      // A-row within tile; also D-col within tile
    const int kgrp = l >> 4;      // 0..3

    // A fragments for the 4 K-steps
    bf16x8 afr[4];
    #pragma unroll
    for (int kk = 0; kk < 4; ++kk) {
        int nl = 16 * wv + row;
        int kc = kk * 4 + kgrp;
        afr[kk] = *(const bf16x8*)(Xs + nl * 128 + ((kc ^ (nl & 7)) << 3));
    }

    f32x4 acc[8];
    #pragma unroll
    for (int nt = 0; nt < 8; ++nt) {
        float b = bias[nt * 16 + row];
        acc[nt] = (f32x4){b, b, b, b};
    }

    #pragma unroll
    for (int nt = 0; nt < 8; ++nt) {
        int col = nt * 16 + row;
        #pragma unroll
        for (int kk = 0; kk < 4; ++kk) {
            int kc = kk * 4 + kgrp;
            bf16x8 bfr = *(const bf16x8*)(Ws + col * 128 + ((kc ^ (col & 7)) << 3));
            acc[nt] = __builtin_amdgcn_mfma_f32_16x16x32_bf16(afr[kk], bfr, acc[nt], 0, 0, 0);
        }
    }

    // epilogue: D[row=(l>>4)*4+r][col=l&15] per tile
    float dv[4];
    if (OMODE == OM_BF16_SR) {
        #pragma unroll
        for (int r = 0; r < 4; ++r) {
            int grow = nb + 16 * wv + kgrp * 4 + r;
            dv[r] = (grow < N) ? dinv[grow] : 0.f;
        }
    }
    #pragma unroll
    for (int nt = 0; nt < 8; ++nt) {
        int gcol = nt * 16 + row;
        #pragma unroll
        for (int r = 0; r < 4; ++r) {
            int grow = nb + 16 * wv + kgrp * 4 + r;
            if (grow < N) {
                float v = acc[nt][r];
                if (OMODE == OM_BF16_SR) v = fmaxf(v, 0.f) * dv[r];
                T[(size_t)grow * OSTRIDE + gcol] = f2us(v);
            }
        }
    }
}

// ---------------- VALU GEMM (f32 in/out) for h1 ----------------
__global__ __launch_bounds__(256) void gemm128f(const float* __restrict__ X,
                                                const float* __restrict__ W,
                                                const float* __restrict__ bias,
                                                float* __restrict__ T, int N) {
    __shared__ float Xsh[HIDF][68];
    const int tid = threadIdx.x;
    const int nb = blockIdx.x * 64;
    {
        const int nloc = tid & 63;
        const int n = nb + nloc;
        const int kq0 = tid >> 6;
        if (n < N) {
            const float4* Xr = (const float4*)(X + (size_t)n * HIDF);
            #pragma unroll
            for (int kq = kq0; kq < 32; kq += 4) {
                float4 v = Xr[kq];
                int k = kq * 4;
                Xsh[k + 0][nloc] = v.x; Xsh[k + 1][nloc] = v.y;
                Xsh[k + 2][nloc] = v.z; Xsh[k + 3][nloc] = v.w;
            }
        } else {
            #pragma unroll
            for (int kq = kq0; kq < 32; kq += 4) {
                int k = kq * 4;
                Xsh[k + 0][nloc] = 0.f; Xsh[k + 1][nloc] = 0.f;
                Xsh[k + 2][nloc] = 0.f; Xsh[k + 3][nloc] = 0.f;
            }
        }
    }
    __syncthreads();

    const int j4  = tid & 31;
    const int sub = tid >> 5;
    const float4* Wrow = (const float4*)W;
    const float4 bv = ((const float4*)bias)[j4];

    float4 acc[8];
    #pragma unroll
    for (int i = 0; i < 8; ++i) acc[i] = bv;

    #pragma unroll 4
    for (int k = 0; k < HIDF; ++k) {
        float4 w = Wrow[k * 32 + j4];
        float xv[8];
        *(float4*)&xv[0] = *(const float4*)&Xsh[k][sub * 8];
        *(float4*)&xv[4] = *(const float4*)&Xsh[k][sub * 8 + 4];
        #pragma unroll
        for (int i = 0; i < 8; ++i) {
            acc[i].x = fmaf(xv[i], w.x, acc[i].x);
            acc[i].y = fmaf(xv[i], w.y, acc[i].y);
            acc[i].z = fmaf(xv[i], w.z, acc[i].z);
            acc[i].w = fmaf(xv[i], w.w, acc[i].w);
        }
    }
    #pragma unroll
    for (int i = 0; i < 8; ++i) {
        int n = nb + sub * 8 + i;
        if (n < N) *((float4*)&T[(size_t)n * HIDF + j4 * 4]) = acc[i];
    }
}

// ---------------- meta: scores -> softmax -> weighted sum + h1 residual -> @Wf + bf ----------------
__global__ __launch_bounds__(256) void meta_kernel(const float* __restrict__ H1,
                                                   const unsigned short* __restrict__ H2B,
                                                   const unsigned short* __restrict__ H3B,
                                                   const float* __restrict__ Wa,
                                                   const float* __restrict__ ba,
                                                   const float* __restrict__ Wf,
                                                   const float* __restrict__ bfb,
                                                   float* __restrict__ out, int N) {
    __shared__ float WfS[HIDF * OUTF];  // 32 KB
    __shared__ float WaS[HIDF];
    __shared__ float hm[4][HIDF];
    const int tid = threadIdx.x;
    for (int i = tid; i < HIDF * OUTF; i += 256) WfS[i] = Wf[i];
    if (tid < HIDF) WaS[tid] = Wa[tid];
    __syncthreads();
    const float bav = ba[0];
    const int w = tid >> 6;
    const int l = tid & 63;
    const float bfv = bfb[l];
    const int iters = (N + 3) >> 2;

    for (int it = blockIdx.x; it < iters; it += gridDim.x) {
        const int n = it * 4 + w;
        __syncthreads();
        if (n < N) {
            const float* h1 = H1 + (size_t)n * HIDF;
            const unsigned short* h2 = H2B + (size_t)n * HIDF;
            const unsigned short* h3 = H3B + (size_t)n * HIDF;
            float h1a = fmaxf(h1[l], 0.f),       h1b = fmaxf(h1[l + 64], 0.f);
            float h2a = fmaxf(us2f(h2[l]), 0.f), h2b = fmaxf(us2f(h2[l + 64]), 0.f);
            float h3a = fmaxf(us2f(h3[l]), 0.f), h3b = fmaxf(us2f(h3[l + 64]), 0.f);
            float s1 = h1a * WaS[l] + h1b * WaS[l + 64];
            float s2 = h2a * WaS[l] + h2b * WaS[l + 64];
            float s3 = h3a * WaS[l] + h3b * WaS[l + 64];
            #pragma unroll
            for (int off = 32; off; off >>= 1) {
                s1 += __shfl_xor(s1, off);
                s2 += __shfl_xor(s2, off);
                s3 += __shfl_xor(s3, off);
            }
            s1 += bav; s2 += bav; s3 += bav;
            float m  = fmaxf(s1, fmaxf(s2, s3));
            float e1 = expf(s1 - m), e2 = expf(s2 - m), e3 = expf(s3 - m);
            float inv = 1.f / (e1 + e2 + e3);
            float w1 = e1 * inv, w2 = e2 * inv, w3 = e3 * inv;
            hm[w][l]      = w1 * h1a + w2 * h2a + w3 * h3a + h1a;
            hm[w][l + 64] = w1 * h1b + w2 * h2b + w3 * h3b + h1b;
        }
        __syncthreads();
        if (n < N) {
            float acc = bfv;
            #pragma unroll
            for (int k = 0; k < HIDF; ++k) acc = fmaf(hm[w][k], WfS[k * OUTF + l], acc);
            out[(size_t)n * OUTF + l] = acc;
        }
    }
}

// ---------------- launch ----------------
extern "C" void kernel_launch(void* const* d_in, const int* in_sizes, int n_in,
                              void* d_out, int out_size, void* d_ws, size_t ws_size,
                              hipStream_t stream) {
    const float* x   = (const float*)d_in[0];
    const int*   ei  = (const int*)d_in[1];
    const float *W1  = (const float*)d_in[2],  *b1  = (const float*)d_in[3];
    const float *W21 = (const float*)d_in[4],  *b21 = (const float*)d_in[5];
    const float *W22 = (const float*)d_in[6],  *b22 = (const float*)d_in[7];
    const float *W31 = (const float*)d_in[8],  *b31 = (const float*)d_in[9];
    const float *W32 = (const float*)d_in[10], *b32 = (const float*)d_in[11];
    const float *W33 = (const float*)d_in[12], *b33 = (const float*)d_in[13];
    const float *Wa  = (const float*)d_in[14], *ba  = (const float*)d_in[15];
    const float *Wf  = (const float*)d_in[16], *bfb = (const float*)d_in[17];

    const int N = in_sizes[0] / HIDF;
    const int E = in_sizes[1] / 2;

    // workspace: ints | DINV | TB23 | PX(f32) | AGA | AGB | H2B | WTB  (~187 MB)
    int*   DEGI    = (int*)d_ws;                          // N
    int*   CURSOR  = DEGI + N;                            // N
    int*   CSR_SRC = CURSOR + N;                          // E
    int*   BSUM    = CSR_SRC + E;                         // 256
    int*   BOFF    = BSUM + 256;                          // 256
    float* DINV    = (float*)(BOFF + 256);                // N
    unsigned short* TB23 = (unsigned short*)(DINV + N);   // N*256 bf16
    float* PX      = (float*)(TB23 + (size_t)N * 256);    // N*128 f32 (becomes H1 in-place)
    unsigned* AGA  = (unsigned*)(PX + (size_t)N * HIDF);  // N*64 uints
    unsigned* AGB  = AGA + (size_t)N * 64;                // N*64 uints
    unsigned* H2B  = AGB + (size_t)N * 64;                // N*64 uints
    unsigned short* WTB = (unsigned short*)(H2B + (size_t)N * 64);  // 5*16384 bf16

    const int gN    = (N + 255) / 256;
    const int gE    = (E + 255) / 256;
    const int gCVT  = (N * 32 + 255) / 256;
    const int gAGG  = (N * 64 + 255) / 256;
    const int gGEMM = (N + 63) / 64;
    const int gMETA = 2048;

    // CSR build + weight pre-transpose
    deg_zero<<<gN, 256, 0, stream>>>(DEGI, N);
    deg_count<<<gE, 256, 0, stream>>>(ei, DEGI, E);
    scanA<<<SCAN_B, 256, 0, stream>>>(DEGI, BSUM, N);
    scanB<<<1, 256, 0, stream>>>(BSUM, BOFF);
    scanC<<<SCAN_B, 256, 0, stream>>>(DEGI, BOFF, CURSOR, DINV, N);
    scatter_kernel<<<gE, 256, 0, stream>>>(ei, CURSOR, CSR_SRC, E);
    cvt_w<<<320, 256, 0, stream>>>(W21, W31, W22, W32, W33, WTB);

    unsigned short* TBX = TB23;   // plain [n][128] bf16 view, reused

    // TBX = bf16(x*dinv); PX = P x  (f32, shared by branches + h1)
    cvt_scale<<<gCVT, 256, 0, stream>>>(x, DINV, TBX, N);
    agg_b<false><<<gAGG, 256, 0, stream>>>(TBX, DINV, CSR_SRC, CURSOR, PX, N);

    // branch layer-1 (MFMA, f32 input converted in staging): TB23 = {g2, g3}
    gemm_mfma<OM_BF16_SR, 256, true><<<gGEMM, 256, 0, stream>>>(PX, WTB,           b21, DINV, TB23,       N);
    gemm_mfma<OM_BF16_SR, 256, true><<<gGEMM, 256, 0, stream>>>(PX, WTB + 16384,   b31, DINV, TB23 + 128, N);
    // fused aggregation: AGA = P g2, AGB = P g3
    agg_dual<<<gAGG, 256, 0, stream>>>(TB23, DINV, CSR_SRC, CURSOR, AGA, AGB, N);

    // h2 finish: H2B = AGA@W22+b22  (MFMA)
    gemm_mfma<OM_BF16, 128, false><<<gGEMM, 256, 0, stream>>>(AGA, WTB + 2 * 16384, b22, DINV, (unsigned short*)H2B, N);
    // h3 second layer: TBX = relu(AGB@W32+b32)*dinv  (MFMA)
    gemm_mfma<OM_BF16_SR, 128, false><<<gGEMM, 256, 0, stream>>>(AGB, WTB + 3 * 16384, b32, DINV, TBX, N);
    // h3 aggregation: AGA = P TBX
    agg_b<true><<<gAGG, 256, 0, stream>>>(TBX, DINV, CSR_SRC, CURSOR, AGA, N);
    // h3 finish: H3B (=AGB) = AGA@W33+b33  (MFMA)
    gemm_mfma<OM_BF16, 128, false><<<gGEMM, 256, 0, stream>>>(AGA, WTB + 4 * 16384, b33, DINV, (unsigned short*)AGB, N);

    // h1: PX <- PX@W1+b1 (VALU f32 in-place; keeps precision headroom)
    gemm128f<<<gGEMM, 256, 0, stream>>>(PX, W1, b1, PX, N);

    // meta combine + final projection
    meta_kernel<<<gMETA, 256, 0, stream>>>(PX, (const unsigned short*)H2B,
                                           (const unsigned short*)AGB, Wa, ba, Wf, bfb,
                                           (float*)d_out, N);
}

// Round 11
// 726.629 us; speedup vs baseline: 23.7440x; 1.0356x over previous
//
#include <hip/hip_runtime.h>
#include <hip/hip_bf16.h>

#define HIDF 128
#define OUTF 64
#define SCAN_B 256   // blocks in hierarchical scan
#define BK_SHIFT 7   // 128 nodes per CSR bucket

typedef __attribute__((ext_vector_type(8))) short bf16x8;
typedef __attribute__((ext_vector_type(4))) float f32x4;

__device__ __forceinline__ float us2f(unsigned u_lo16) {           // bf16 bits in low 16
    return __uint_as_float(u_lo16 << 16);
}
__device__ __forceinline__ unsigned short f2us(float f) {          // RNE f32 -> bf16 bits
    __hip_bfloat16 h = __float2bfloat16(f);
    return *reinterpret_cast<unsigned short*>(&h);
}
__device__ __forceinline__ unsigned pack2(float a, float b) {      // [lo=a, hi=b]
    return (unsigned)f2us(a) | ((unsigned)f2us(b) << 16);
}

// ---------------- degree / scan ----------------
__global__ __launch_bounds__(256) void deg_zero(int* __restrict__ d, int N) {
    int i = blockIdx.x * 256 + threadIdx.x;
    if (i < N) d[i] = 0;
}

__global__ __launch_bounds__(256) void deg_count(const int* __restrict__ ei, int* __restrict__ d, int E) {
    int e = blockIdx.x * 256 + threadIdx.x;
    if (e < E) atomicAdd(&d[ei[E + e]], 1);
}

__global__ __launch_bounds__(256) void scanA(const int* __restrict__ degi, int* __restrict__ blocksum, int N) {
    __shared__ int red[256];
    const int b = blockIdx.x;
    const int chunk = (N + SCAN_B - 1) / SCAN_B;
    const int lo = b * chunk, hi = min(lo + chunk, N);
    int s = 0;
    for (int i = lo + threadIdx.x; i < hi; i += 256) s += degi[i];
    red[threadIdx.x] = s;
    __syncthreads();
    for (int off = 128; off; off >>= 1) {
        if (threadIdx.x < off) red[threadIdx.x] += red[threadIdx.x + off];
        __syncthreads();
    }
    if (threadIdx.x == 0) blocksum[b] = red[0];
}

__global__ __launch_bounds__(256) void scanB(const int* __restrict__ blocksum, int* __restrict__ blockoff) {
    __shared__ int ps[256];
    const int t = threadIdx.x;
    ps[t] = blocksum[t];
    __syncthreads();
    for (int off = 1; off < 256; off <<= 1) {
        int v = ps[t];
        int u = (t >= off) ? ps[t - off] : 0;
        __syncthreads();
        ps[t] = v + u;
        __syncthreads();
    }
    blockoff[t] = (t == 0) ? 0 : ps[t - 1];
}

__global__ __launch_bounds__(256) void scanC(const int* __restrict__ degi,
                                             const int* __restrict__ blockoff,
                                             int* __restrict__ cursor,
                                             float* __restrict__ dinv, int N) {
    __shared__ int ps[256];
    const int b = blockIdx.x;
    const int chunk = (N + SCAN_B - 1) / SCAN_B;
    const int lo = b * chunk, hi = min(lo + chunk, N);
    const int tchunk = (chunk + 255) / 256;
    const int tlo = lo + threadIdx.x * tchunk;
    const int thi = min(tlo + tchunk, hi);
    int s = 0;
    for (int i = tlo; i < thi; ++i) s += degi[i];
    ps[threadIdx.x] = s;
    __syncthreads();
    for (int off = 1; off < 256; off <<= 1) {
        int v = ps[threadIdx.x];
        int u = (threadIdx.x >= off) ? ps[threadIdx.x - off] : 0;
        __syncthreads();
        ps[threadIdx.x] = v + u;
        __syncthreads();
    }
    int base = blockoff[b] + ((threadIdx.x == 0) ? 0 : ps[threadIdx.x - 1]);
    for (int i = tlo; i < thi; ++i) {
        int d = degi[i];
        cursor[i] = base;
        base += d;
        dinv[i] = rsqrtf((float)d + 1.f);
    }
}

// ---------------- bucketed CSR scatter ----------------
// bcur[b*64] = CSR row-start of first node in bucket b (padded x64 to spread L2 atomic channels)
__global__ __launch_bounds__(256) void bcur_init(const int* __restrict__ cursor,
                                                 int* __restrict__ bcur, int N, int NBK) {
    int b = blockIdx.x * 256 + threadIdx.x;
    if (b < NBK) bcur[b * 64] = cursor[b << BK_SHIFT];
}

// pass 1: scatter (src,dst) into bucket-grouped regions of EDG
__global__ __launch_bounds__(256) void bucket_scatter(const int* __restrict__ ei,
                                                      int* __restrict__ bcur,
                                                      int2* __restrict__ edg, int E) {
    int e = blockIdx.x * 256 + threadIdx.x;
    if (e >= E) return;
    int src = ei[e];
    int dst = ei[E + e];
    int pos = atomicAdd(&bcur[(dst >> BK_SHIFT) * 64], 1);
    edg[pos] = make_int2(src, dst);
}

// pass 2: within bucket-grouped order, place src at final CSR position
__global__ __launch_bounds__(256) void final_scatter(const int2* __restrict__ edg,
                                                     int* __restrict__ cursor,
                                                     int* __restrict__ csr_src, int E) {
    int p = blockIdx.x * 256 + threadIdx.x;
    if (p >= E) return;
    int2 sd = edg[p];
    int pos = atomicAdd(&cursor[sd.y], 1);
    csr_src[pos] = sd.x;
}

// ---------------- convert: TB[n,:] = bf16( x[n,:] * dinv[n] ) ----------------
__global__ __launch_bounds__(256) void cvt_scale(const float* __restrict__ X,
                                                 const float* __restrict__ dinv,
                                                 unsigned short* __restrict__ TB, int N) {
    int g = blockIdx.x * 256 + threadIdx.x;   // float4-group index
    if (g >= N * 32) return;
    int n = g >> 5;
    float dv = dinv[n];
    float4 v = ((const float4*)X)[g];
    ushort4 o;
    o.x = f2us(v.x * dv); o.y = f2us(v.y * dv);
    o.z = f2us(v.z * dv); o.w = f2us(v.w * dv);
    ((ushort4*)TB)[g] = o;
}

// ---------------- convert 6 weight matrices f32 [k][n] -> bf16 transposed [n][k] ----------------
__global__ __launch_bounds__(256) void cvt_w(const float* __restrict__ Wa0,
                                             const float* __restrict__ Wa1,
                                             const float* __restrict__ Wa2,
                                             const float* __restrict__ Wa3,
                                             const float* __restrict__ Wa4,
                                             const float* __restrict__ Wa5,
                                             unsigned short* __restrict__ WTB) {
    int t = blockIdx.x * 256 + threadIdx.x;
    if (t >= 6 * 16384) return;
    int m = t >> 14, local = t & 16383;
    int n = local >> 7, k = local & 127;
    const float* src = (m == 0) ? Wa0 : (m == 1) ? Wa1 : (m == 2) ? Wa2
                     : (m == 3) ? Wa3 : (m == 4) ? Wa4 : Wa5;
    WTB[t] = f2us(src[k * 128 + n]);
}

// ---------------- single CSR aggregation over bf16 rows (pre-scaled by dinv[src]) ----------------
template <bool OUT_BF16>
__global__ __launch_bounds__(256) void agg_b(const unsigned short* __restrict__ TB,
                                             const float* __restrict__ dinv,
                                             const int* __restrict__ csr_src,
                                             const int* __restrict__ rend,
                                             void* __restrict__ O, int N) {
    const int n = (blockIdx.x * 256 + threadIdx.x) >> 6;
    const int lane = threadIdx.x & 63;
    if (n >= N) return;
    const int start = (n == 0) ? 0 : rend[n - 1];
    const int end   = rend[n];
    const unsigned* Tv = (const unsigned*)TB;   // row = 64 uints (2 bf16 each)

    float ax0 = 0.f, ay0 = 0.f, ax1 = 0.f, ay1 = 0.f;
    int e = start;
    for (; e + 8 <= end; e += 8) {
        int s0 = csr_src[e + 0], s1 = csr_src[e + 1], s2 = csr_src[e + 2], s3 = csr_src[e + 3];
        int s4 = csr_src[e + 4], s5 = csr_src[e + 5], s6 = csr_src[e + 6], s7 = csr_src[e + 7];
        unsigned v0 = Tv[(size_t)s0 * 64 + lane];
        unsigned v1 = Tv[(size_t)s1 * 64 + lane];
        unsigned v2 = Tv[(size_t)s2 * 64 + lane];
        unsigned v3 = Tv[(size_t)s3 * 64 + lane];
        unsigned v4 = Tv[(size_t)s4 * 64 + lane];
        unsigned v5 = Tv[(size_t)s5 * 64 + lane];
        unsigned v6 = Tv[(size_t)s6 * 64 + lane];
        unsigned v7 = Tv[(size_t)s7 * 64 + lane];
        ax0 += us2f(v0 & 0xffffu); ay0 += __uint_as_float(v0 & 0xffff0000u);
        ax1 += us2f(v1 & 0xffffu); ay1 += __uint_as_float(v1 & 0xffff0000u);
        ax0 += us2f(v2 & 0xffffu); ay0 += __uint_as_float(v2 & 0xffff0000u);
        ax1 += us2f(v3 & 0xffffu); ay1 += __uint_as_float(v3 & 0xffff0000u);
        ax0 += us2f(v4 & 0xffffu); ay0 += __uint_as_float(v4 & 0xffff0000u);
        ax1 += us2f(v5 & 0xffffu); ay1 += __uint_as_float(v5 & 0xffff0000u);
        ax0 += us2f(v6 & 0xffffu); ay0 += __uint_as_float(v6 & 0xffff0000u);
        ax1 += us2f(v7 & 0xffffu); ay1 += __uint_as_float(v7 & 0xffff0000u);
    }
    if (e + 4 <= end) {
        int s0 = csr_src[e + 0], s1 = csr_src[e + 1], s2 = csr_src[e + 2], s3 = csr_src[e + 3];
        unsigned v0 = Tv[(size_t)s0 * 64 + lane];
        unsigned v1 = Tv[(size_t)s1 * 64 + lane];
        unsigned v2 = Tv[(size_t)s2 * 64 + lane];
        unsigned v3 = Tv[(size_t)s3 * 64 + lane];
        ax0 += us2f(v0 & 0xffffu); ay0 += __uint_as_float(v0 & 0xffff0000u);
        ax1 += us2f(v1 & 0xffffu); ay1 += __uint_as_float(v1 & 0xffff0000u);
        ax0 += us2f(v2 & 0xffffu); ay0 += __uint_as_float(v2 & 0xffff0000u);
        ax1 += us2f(v3 & 0xffffu); ay1 += __uint_as_float(v3 & 0xffff0000u);
        e += 4;
    }
    for (; e < end; ++e) {
        int s = csr_src[e];
        unsigned v = Tv[(size_t)s * 64 + lane];
        ax0 += us2f(v & 0xffffu);
        ay0 += __uint_as_float(v & 0xffff0000u);
    }
    unsigned sv = Tv[(size_t)n * 64 + lane];
    ax0 += us2f(sv & 0xffffu);
    ay0 += __uint_as_float(sv & 0xffff0000u);
    const float dv = dinv[n];
    float ox = (ax0 + ax1) * dv;
    float oy = (ay0 + ay1) * dv;
    if (OUT_BF16) {
        ((unsigned*)O)[(size_t)n * 64 + lane] = pack2(ox, oy);
    } else {
        float2 o; o.x = ox; o.y = oy;
        ((float2*)O)[(size_t)n * 64 + lane] = o;
    }
}

// ---------------- dual CSR aggregation: TB23[n][2][128] bf16 interleaved rows ----------------
__global__ __launch_bounds__(256) void agg_dual(const unsigned short* __restrict__ TB23,
                                                const float* __restrict__ dinv,
                                                const int* __restrict__ csr_src,
                                                const int* __restrict__ rend,
                                                unsigned* __restrict__ OA,
                                                unsigned* __restrict__ OB, int N) {
    const int n = (blockIdx.x * 256 + threadIdx.x) >> 6;
    const int lane = threadIdx.x & 63;
    if (n >= N) return;
    const int start = (n == 0) ? 0 : rend[n - 1];
    const int end   = rend[n];
    const unsigned* Tv = (const unsigned*)TB23;   // node row = 128 uints: [0..63]=g2, [64..127]=g3

    float ax2 = 0.f, ay2 = 0.f, bx2 = 0.f, by2 = 0.f;
    float ax3 = 0.f, ay3 = 0.f, bx3 = 0.f, by3 = 0.f;
    int e = start;
    for (; e + 4 <= end; e += 4) {
        int s0 = csr_src[e + 0], s1 = csr_src[e + 1], s2 = csr_src[e + 2], s3 = csr_src[e + 3];
        unsigned a0 = Tv[(size_t)s0 * 128 + lane];
        unsigned c0 = Tv[(size_t)s0 * 128 + 64 + lane];
        unsigned a1 = Tv[(size_t)s1 * 128 + lane];
        unsigned c1 = Tv[(size_t)s1 * 128 + 64 + lane];
        unsigned a2 = Tv[(size_t)s2 * 128 + lane];
        unsigned c2 = Tv[(size_t)s2 * 128 + 64 + lane];
        unsigned a3 = Tv[(size_t)s3 * 128 + lane];
        unsigned c3 = Tv[(size_t)s3 * 128 + 64 + lane];
        ax2 += us2f(a0 & 0xffffu); ay2 += __uint_as_float(a0 & 0xffff0000u);
        ax3 += us2f(c0 & 0xffffu); ay3 += __uint_as_float(c0 & 0xffff0000u);
        bx2 += us2f(a1 & 0xffffu); by2 += __uint_as_float(a1 & 0xffff0000u);
        bx3 += us2f(c1 & 0xffffu); by3 += __uint_as_float(c1 & 0xffff0000u);
        ax2 += us2f(a2 & 0xffffu); ay2 += __uint_as_float(a2 & 0xffff0000u);
        ax3 += us2f(c2 & 0xffffu); ay3 += __uint_as_float(c2 & 0xffff0000u);
        bx2 += us2f(a3 & 0xffffu); by2 += __uint_as_float(a3 & 0xffff0000u);
        bx3 += us2f(c3 & 0xffffu); by3 += __uint_as_float(c3 & 0xffff0000u);
    }
    for (; e < end; ++e) {
        int s = csr_src[e];
        unsigned a = Tv[(size_t)s * 128 + lane];
        unsigned c = Tv[(size_t)s * 128 + 64 + lane];
        ax2 += us2f(a & 0xffffu); ay2 += __uint_as_float(a & 0xffff0000u);
        ax3 += us2f(c & 0xffffu); ay3 += __uint_as_float(c & 0xffff0000u);
    }
    {   // self-loop
        unsigned a = Tv[(size_t)n * 128 + lane];
        unsigned c = Tv[(size_t)n * 128 + 64 + lane];
        ax2 += us2f(a & 0xffffu); ay2 += __uint_as_float(a & 0xffff0000u);
        ax3 += us2f(c & 0xffffu); ay3 += __uint_as_float(c & 0xffff0000u);
    }
    const float dv = dinv[n];
    OA[(size_t)n * 64 + lane] = pack2((ax2 + bx2) * dv, (ay2 + by2) * dv);
    OB[(size_t)n * 64 + lane] = pack2((ax3 + bx3) * dv, (ay3 + by3) * dv);
}

// ---------------- MFMA GEMM: T = X @ W + b (bf16 in via LDS; out bf16 or f32) ----------------
// 64-node tile x 128 cols; 4 waves x (16 rows, 8 n-tiles, K=128 in 4 steps of 32).
// LDS: Xs 16KB + Ws 32KB, XOR-swizzled (chunk ^= row&7) on write AND read.
#define OM_F32 0
#define OM_BF16 1
#define OM_BF16_SR 2
template <int OMODE, int OSTRIDE>
__global__ __launch_bounds__(256) void gemm_mfma(const unsigned short* __restrict__ Xb,
                                                 const unsigned short* __restrict__ WT,  // [n][k] bf16
                                                 const float* __restrict__ bias,
                                                 const float* __restrict__ dinv,
                                                 void* __restrict__ T, int N) {
    __shared__ unsigned short Xs[64 * 128];   // 16 KB
    __shared__ unsigned short Ws[128 * 128];  // 32 KB
    const int tid = threadIdx.x;
    const int nb = blockIdx.x * 64;

    // stage W transposed (2048 x 16B chunks), swizzled
    for (int c = tid; c < 2048; c += 256) {
        int n = c >> 4, kc = c & 15;
        ((uint4*)Ws)[(n << 4) | (kc ^ (n & 7))] = ((const uint4*)WT)[c];
    }
    // stage X (1024 x 16B bf16 chunks), swizzled
    for (int c = tid; c < 1024; c += 256) {
        int nl = c >> 4, kc = c & 15;
        int n = nb + nl;
        uint4 v = make_uint4(0u, 0u, 0u, 0u);
        if (n < N) v = ((const uint4*)(Xb + (size_t)n * HIDF))[kc];
        ((uint4*)Xs)[(nl << 4) | (kc ^ (nl & 7))] = v;
    }
    __syncthreads();

    const int wv   = tid >> 6;    // wave id: rows 16wv..16wv+15
    const int l    = tid & 63;
    const int row  = l & 15;      // A-row within tile; also D-col within tile
    const int kgrp = l >> 4;      // 0..3

    bf16x8 afr[4];
    #pragma unroll
    for (int kk = 0; kk < 4; ++kk) {
        int nl = 16 * wv + row;
        int kc = kk * 4 + kgrp;
        afr[kk] = *(const bf16x8*)(Xs + nl * 128 + ((kc ^ (nl & 7)) << 3));
    }

    f32x4 acc[8];
    #pragma unroll
    for (int nt = 0; nt < 8; ++nt) {
        float b = bias[nt * 16 + row];
        acc[nt] = (f32x4){b, b, b, b};
    }

    #pragma unroll
    for (int nt = 0; nt < 8; ++nt) {
        int col = nt * 16 + row;
        #pragma unroll
        for (int kk = 0; kk < 4; ++kk) {
            int kc = kk * 4 + kgrp;
            bf16x8 bfr = *(const bf16x8*)(Ws + col * 128 + ((kc ^ (col & 7)) << 3));
            acc[nt] = __builtin_amdgcn_mfma_f32_16x16x32_bf16(afr[kk], bfr, acc[nt], 0, 0, 0);
        }
    }

    // epilogue: D[row=(l>>4)*4+r][col=l&15] per tile
    float dv[4];
    if (OMODE == OM_BF16_SR) {
        #pragma unroll
        for (int r = 0; r < 4; ++r) {
            int grow = nb + 16 * wv + kgrp * 4 + r;
            dv[r] = (grow < N) ? dinv[grow] : 0.f;
        }
    }
    #pragma unroll
    for (int nt = 0; nt < 8; ++nt) {
        int gcol = nt * 16 + row;
        #pragma unroll
        for (int r = 0; r < 4; ++r) {
            int grow = nb + 16 * wv + kgrp * 4 + r;
            if (grow < N) {
                float v = acc[nt][r];
                if (OMODE == OM_BF16_SR) v = fmaxf(v, 0.f) * dv[r];
                if (OMODE == OM_F32) {
                    ((float*)T)[(size_t)grow * OSTRIDE + gcol] = v;
                } else {
                    ((unsigned short*)T)[(size_t)grow * OSTRIDE + gcol] = f2us(v);
                }
            }
        }
    }
}

// ---------------- meta: scores -> softmax -> weighted sum + h1 residual -> @Wf + bf ----------------
__global__ __launch_bounds__(256) void meta_kernel(const float* __restrict__ H1,
                                                   const unsigned short* __restrict__ H2B,
                                                   const unsigned short* __restrict__ H3B,
                                                   const float* __restrict__ Wa,
                                                   const float* __restrict__ ba,
                                                   const float* __restrict__ Wf,
                                                   const float* __restrict__ bfb,
                                                   float* __restrict__ out, int N) {
    __shared__ float WfS[HIDF * OUTF];  // 32 KB
    __shared__ float WaS[HIDF];
    __shared__ float hm[4][HIDF];
    const int tid = threadIdx.x;
    for (int i = tid; i < HIDF * OUTF; i += 256) WfS[i] = Wf[i];
    if (tid < HIDF) WaS[tid] = Wa[tid];
    __syncthreads();
    const float bav = ba[0];
    const int w = tid >> 6;
    const int l = tid & 63;
    const float bfv = bfb[l];
    const int iters = (N + 3) >> 2;

    for (int it = blockIdx.x; it < iters; it += gridDim.x) {
        const int n = it * 4 + w;
        __syncthreads();
        if (n < N) {
            const float* h1 = H1 + (size_t)n * HIDF;
            const unsigned short* h2 = H2B + (size_t)n * HIDF;
            const unsigned short* h3 = H3B + (size_t)n * HIDF;
            float h1a = fmaxf(h1[l], 0.f),       h1b = fmaxf(h1[l + 64], 0.f);
            float h2a = fmaxf(us2f(h2[l]), 0.f), h2b = fmaxf(us2f(h2[l + 64]), 0.f);
            float h3a = fmaxf(us2f(h3[l]), 0.f), h3b = fmaxf(us2f(h3[l + 64]), 0.f);
            float s1 = h1a * WaS[l] + h1b * WaS[l + 64];
            float s2 = h2a * WaS[l] + h2b * WaS[l + 64];
            float s3 = h3a * WaS[l] + h3b * WaS[l + 64];
            #pragma unroll
            for (int off = 32; off; off >>= 1) {
                s1 += __shfl_xor(s1, off);
                s2 += __shfl_xor(s2, off);
                s3 += __shfl_xor(s3, off);
            }
            s1 += bav; s2 += bav; s3 += bav;
            float m  = fmaxf(s1, fmaxf(s2, s3));
            float e1 = expf(s1 - m), e2 = expf(s2 - m), e3 = expf(s3 - m);
            float inv = 1.f / (e1 + e2 + e3);
            float w1 = e1 * inv, w2 = e2 * inv, w3 = e3 * inv;
            hm[w][l]      = w1 * h1a + w2 * h2a + w3 * h3a + h1a;
            hm[w][l + 64] = w1 * h1b + w2 * h2b + w3 * h3b + h1b;
        }
        __syncthreads();
        if (n < N) {
            float acc = bfv;
            #pragma unroll
            for (int k = 0; k < HIDF; ++k) acc = fmaf(hm[w][k], WfS[k * OUTF + l], acc);
            out[(size_t)n * OUTF + l] = acc;
        }
    }
}

// ---------------- launch ----------------
extern "C" void kernel_launch(void* const* d_in, const int* in_sizes, int n_in,
                              void* d_out, int out_size, void* d_ws, size_t ws_size,
                              hipStream_t stream) {
    const float* x   = (const float*)d_in[0];
    const int*   ei  = (const int*)d_in[1];
    const float *W1  = (const float*)d_in[2],  *b1  = (const float*)d_in[3];
    const float *W21 = (const float*)d_in[4],  *b21 = (const float*)d_in[5];
    const float *W22 = (const float*)d_in[6],  *b22 = (const float*)d_in[7];
    const float *W31 = (const float*)d_in[8],  *b31 = (const float*)d_in[9];
    const float *W32 = (const float*)d_in[10], *b32 = (const float*)d_in[11];
    const float *W33 = (const float*)d_in[12], *b33 = (const float*)d_in[13];
    const float *Wa  = (const float*)d_in[14], *ba  = (const float*)d_in[15];
    const float *Wf  = (const float*)d_in[16], *bfb = (const float*)d_in[17];

    const int N = in_sizes[0] / HIDF;
    const int E = in_sizes[1] / 2;
    const int NBK = (N + 127) >> BK_SHIFT;

    // workspace: ints | DINV | TB23 (aliased later by H1F f32) | PXB | AGA | AGB | H2B | WTB
    int*   DEGI    = (int*)d_ws;                          // N
    int*   CURSOR  = DEGI + N;                            // N
    int*   CSR_SRC = CURSOR + N;                          // E
    int2*  EDG     = (int2*)(CSR_SRC + E);                // E int2
    int*   BCUR    = (int*)(EDG + E);                     // NBK*64 (padded)
    int*   BSUM    = BCUR + 1024 * 64;                    // 256
    int*   BOFF    = BSUM + 256;                          // 256
    float* DINV    = (float*)(BOFF + 256);                // N
    unsigned short* TB23 = (unsigned short*)(DINV + N);   // N*256 bf16 (later: H1F f32 N*128)
    unsigned* PXB  = (unsigned*)(TB23 + (size_t)N * 256); // N*64 uints (bf16 pairs)
    unsigned* AGA  = PXB + (size_t)N * 64;                // N*64 uints
    unsigned* AGB  = AGA + (size_t)N * 64;                // N*64 uints
    unsigned* H2B  = AGB + (size_t)N * 64;                // N*64 uints
    unsigned short* WTB = (unsigned short*)(H2B + (size_t)N * 64);  // 6*16384 bf16

    const int gN    = (N + 255) / 256;
    const int gE    = (E + 255) / 256;
    const int gCVT  = (N * 32 + 255) / 256;
    const int gAGG  = (N * 64 + 255) / 256;
    const int gGEMM = (N + 63) / 64;
    const int gMETA = 2048;

    // CSR build (bucketed) + weight pre-transpose
    deg_zero<<<gN, 256, 0, stream>>>(DEGI, N);
    deg_count<<<gE, 256, 0, stream>>>(ei, DEGI, E);
    scanA<<<SCAN_B, 256, 0, stream>>>(DEGI, BSUM, N);
    scanB<<<1, 256, 0, stream>>>(BSUM, BOFF);
    scanC<<<SCAN_B, 256, 0, stream>>>(DEGI, BOFF, CURSOR, DINV, N);
    bcur_init<<<(NBK + 255) / 256, 256, 0, stream>>>(CURSOR, BCUR, N, NBK);
    bucket_scatter<<<gE, 256, 0, stream>>>(ei, BCUR, EDG, E);
    final_scatter<<<gE, 256, 0, stream>>>(EDG, CURSOR, CSR_SRC, E);
    cvt_w<<<384, 256, 0, stream>>>(W21, W31, W22, W32, W33, W1, WTB);

    unsigned short* TBX = TB23;   // plain [n][128] bf16 view of TB23 region

    // TBX = bf16(x*dinv); PXB = bf16( P x )
    cvt_scale<<<gCVT, 256, 0, stream>>>(x, DINV, TBX, N);
    agg_b<true><<<gAGG, 256, 0, stream>>>(TBX, DINV, CSR_SRC, CURSOR, PXB, N);

    // branch layer-1: TB23 = {g2, g3} = {relu(PXB@W21)*dinv, relu(PXB@W31)*dinv}
    gemm_mfma<OM_BF16_SR, 256><<<gGEMM, 256, 0, stream>>>((unsigned short*)PXB, WTB,         b21, DINV, TB23,       N);
    gemm_mfma<OM_BF16_SR, 256><<<gGEMM, 256, 0, stream>>>((unsigned short*)PXB, WTB + 16384, b31, DINV, TB23 + 128, N);
    // fused aggregation: AGA = P g2, AGB = P g3
    agg_dual<<<gAGG, 256, 0, stream>>>(TB23, DINV, CSR_SRC, CURSOR, AGA, AGB, N);

    // h2 finish: H2B = AGA@W22+b22
    gemm_mfma<OM_BF16, 128><<<gGEMM, 256, 0, stream>>>((unsigned short*)AGA, WTB + 2 * 16384, b22, DINV, H2B, N);
    // h3 second layer: TBX = relu(AGB@W32+b32)*dinv
    gemm_mfma<OM_BF16_SR, 128><<<gGEMM, 256, 0, stream>>>((unsigned short*)AGB, WTB + 3 * 16384, b32, DINV, TBX, N);
    // h3 aggregation: AGA = P TBX
    agg_b<true><<<gAGG, 256, 0, stream>>>(TBX, DINV, CSR_SRC, CURSOR, AGA, N);
    // h3 finish: H3B (=AGB) = AGA@W33+b33
    gemm_mfma<OM_BF16, 128><<<gGEMM, 256, 0, stream>>>((unsigned short*)AGA, WTB + 4 * 16384, b33, DINV, AGB, N);

    // h1: H1F (f32, aliases TB23 region; TBX dead) = PXB@W1+b1
    float* H1F = (float*)TB23;
    gemm_mfma<OM_F32, 128><<<gGEMM, 256, 0, stream>>>((unsigned short*)PXB, WTB + 5 * 16384, b1, DINV, H1F, N);

    // meta combine + final projection
    meta_kernel<<<gMETA, 256, 0, stream>>>(H1F, (const unsigned short*)H2B,
                                           (const unsigned short*)AGB, Wa, ba, Wf, bfb,
                                           (float*)d_out, N);
}

// Round 12
// 705.786 us; speedup vs baseline: 24.4452x; 1.0295x over previous
//
#include <hip/hip_runtime.h>
#include <hip/hip_bf16.h>

#define HIDF 128
#define OUTF 64
#define SCAN_B 256   // blocks in hierarchical scan
#define BK_SHIFT 7   // 128 nodes per CSR bucket

typedef __attribute__((ext_vector_type(8))) short bf16x8;
typedef __attribute__((ext_vector_type(4))) float f32x4;

__device__ __forceinline__ float us2f(unsigned u_lo16) {           // bf16 bits in low 16
    return __uint_as_float(u_lo16 << 16);
}
__device__ __forceinline__ float hi2f(unsigned u) {                // bf16 bits in high 16
    return __uint_as_float(u & 0xffff0000u);
}
__device__ __forceinline__ unsigned short f2us(float f) {          // RNE f32 -> bf16 bits
    __hip_bfloat16 h = __float2bfloat16(f);
    return *reinterpret_cast<unsigned short*>(&h);
}
__device__ __forceinline__ unsigned pack2(float a, float b) {      // [lo=a, hi=b]
    return (unsigned)f2us(a) | ((unsigned)f2us(b) << 16);
}

// ---------------- degree / scan ----------------
__global__ __launch_bounds__(256) void deg_zero(int* __restrict__ d, int N) {
    int i = blockIdx.x * 256 + threadIdx.x;
    if (i < N) d[i] = 0;
}

__global__ __launch_bounds__(256) void deg_count(const int* __restrict__ ei, int* __restrict__ d, int E) {
    int e = blockIdx.x * 256 + threadIdx.x;
    if (e < E) atomicAdd(&d[ei[E + e]], 1);
}

__global__ __launch_bounds__(256) void scanA(const int* __restrict__ degi, int* __restrict__ blocksum, int N) {
    __shared__ int red[256];
    const int b = blockIdx.x;
    const int chunk = (N + SCAN_B - 1) / SCAN_B;
    const int lo = b * chunk, hi = min(lo + chunk, N);
    int s = 0;
    for (int i = lo + threadIdx.x; i < hi; i += 256) s += degi[i];
    red[threadIdx.x] = s;
    __syncthreads();
    for (int off = 128; off; off >>= 1) {
        if (threadIdx.x < off) red[threadIdx.x] += red[threadIdx.x + off];
        __syncthreads();
    }
    if (threadIdx.x == 0) blocksum[b] = red[0];
}

__global__ __launch_bounds__(256) void scanB(const int* __restrict__ blocksum, int* __restrict__ blockoff) {
    __shared__ int ps[256];
    const int t = threadIdx.x;
    ps[t] = blocksum[t];
    __syncthreads();
    for (int off = 1; off < 256; off <<= 1) {
        int v = ps[t];
        int u = (t >= off) ? ps[t - off] : 0;
        __syncthreads();
        ps[t] = v + u;
        __syncthreads();
    }
    blockoff[t] = (t == 0) ? 0 : ps[t - 1];
}

__global__ __launch_bounds__(256) void scanC(const int* __restrict__ degi,
                                             const int* __restrict__ blockoff,
                                             int* __restrict__ cursor,
                                             float* __restrict__ dinv, int N) {
    __shared__ int ps[256];
    const int b = blockIdx.x;
    const int chunk = (N + SCAN_B - 1) / SCAN_B;
    const int lo = b * chunk, hi = min(lo + chunk, N);
    const int tchunk = (chunk + 255) / 256;
    const int tlo = lo + threadIdx.x * tchunk;
    const int thi = min(tlo + tchunk, hi);
    int s = 0;
    for (int i = tlo; i < thi; ++i) s += degi[i];
    ps[threadIdx.x] = s;
    __syncthreads();
    for (int off = 1; off < 256; off <<= 1) {
        int v = ps[threadIdx.x];
        int u = (threadIdx.x >= off) ? ps[threadIdx.x - off] : 0;
        __syncthreads();
        ps[threadIdx.x] = v + u;
        __syncthreads();
    }
    int base = blockoff[b] + ((threadIdx.x == 0) ? 0 : ps[threadIdx.x - 1]);
    for (int i = tlo; i < thi; ++i) {
        int d = degi[i];
        cursor[i] = base;
        base += d;
        dinv[i] = rsqrtf((float)d + 1.f);
    }
}

// ---------------- bucketed CSR scatter (packed 4B records) ----------------
__global__ __launch_bounds__(256) void bcur_init(const int* __restrict__ cursor,
                                                 int* __restrict__ bcur, int N, int NBK) {
    int b = blockIdx.x * 256 + threadIdx.x;
    if (b < NBK) bcur[b * 64] = cursor[b << BK_SHIFT];
}

// pass 1: scatter packed (src<<7 | dst&127) into bucket-grouped regions of EDG
__global__ __launch_bounds__(256) void bucket_scatter(const int* __restrict__ ei,
                                                      int* __restrict__ bcur,
                                                      unsigned* __restrict__ edg, int E) {
    int e = blockIdx.x * 256 + threadIdx.x;
    if (e >= E) return;
    int src = ei[e];
    int dst = ei[E + e];
    int pos = atomicAdd(&bcur[(dst >> BK_SHIFT) * 64], 1);
    edg[pos] = ((unsigned)src << BK_SHIFT) | (unsigned)(dst & ((1 << BK_SHIFT) - 1));
}

// pass 2: one block per bucket; reconstruct dst, place src at final CSR position
__global__ __launch_bounds__(256) void final_scatter_b(const unsigned* __restrict__ edg,
                                                       const int* __restrict__ bcur,  // bucket ends
                                                       int* __restrict__ cursor,
                                                       int* __restrict__ csr_src) {
    const int b = blockIdx.x;
    __shared__ int sstart;
    if (threadIdx.x == 0) sstart = cursor[b << BK_SHIFT];  // unmutated: only this block touches bucket b
    __syncthreads();
    const int bstart = sstart;
    const int bend   = bcur[b * 64];
    const int base   = b << BK_SHIFT;
    for (int p = bstart + threadIdx.x; p < bend; p += 256) {
        unsigned u = edg[p];
        int src = (int)(u >> BK_SHIFT);
        int dst = base | (int)(u & ((1u << BK_SHIFT) - 1));
        int pos = atomicAdd(&cursor[dst], 1);
        csr_src[pos] = src;
    }
}

// ---------------- convert: TB[n,:] = bf16( x[n,:] * dinv[n] ) ----------------
__global__ __launch_bounds__(256) void cvt_scale(const float* __restrict__ X,
                                                 const float* __restrict__ dinv,
                                                 unsigned short* __restrict__ TB, int N) {
    int g = blockIdx.x * 256 + threadIdx.x;   // float4-group index
    if (g >= N * 32) return;
    int n = g >> 5;
    float dv = dinv[n];
    float4 v = ((const float4*)X)[g];
    ushort4 o;
    o.x = f2us(v.x * dv); o.y = f2us(v.y * dv);
    o.z = f2us(v.z * dv); o.w = f2us(v.w * dv);
    ((ushort4*)TB)[g] = o;
}

// ---------------- convert 6 weight matrices f32 [k][n] -> bf16 transposed [n][k] ----------------
__global__ __launch_bounds__(256) void cvt_w(const float* __restrict__ Wa0,
                                             const float* __restrict__ Wa1,
                                             const float* __restrict__ Wa2,
                                             const float* __restrict__ Wa3,
                                             const float* __restrict__ Wa4,
                                             const float* __restrict__ Wa5,
                                             unsigned short* __restrict__ WTB) {
    int t = blockIdx.x * 256 + threadIdx.x;
    if (t >= 6 * 16384) return;
    int m = t >> 14, local = t & 16383;
    int n = local >> 7, k = local & 127;
    const float* src = (m == 0) ? Wa0 : (m == 1) ? Wa1 : (m == 2) ? Wa2
                     : (m == 3) ? Wa3 : (m == 4) ? Wa4 : Wa5;
    WTB[t] = f2us(src[k * 128 + n]);
}

// ---------------- single CSR aggregation, paired-edge uint2 gather ----------------
// O[n,:] = bf16( dinv[n] * ( sum_src TB[src,:] + TB[n,:] ) ); rows pre-scaled by dinv[src].
// Wave halves process even/odd edges; lane owns an 8B (4-bf16) slot; shfl-combine at end.
__global__ __launch_bounds__(256) void agg_b2(const unsigned short* __restrict__ TB,
                                              const float* __restrict__ dinv,
                                              const int* __restrict__ csr_src,
                                              const int* __restrict__ rend,
                                              unsigned* __restrict__ O, int N) {
    const int n = (blockIdx.x * 256 + threadIdx.x) >> 6;
    const int l = threadIdx.x & 63;
    if (n >= N) return;
    const int half = l >> 5;
    const int sl   = l & 31;
    const int start = (n == 0) ? 0 : rend[n - 1];
    const int end   = rend[n];
    const uint2* Tv = (const uint2*)TB;   // row = 32 uint2 (256 B)

    float a0 = 0.f, a1 = 0.f, a2 = 0.f, a3 = 0.f;
    int e = start;
    for (; e + 8 <= end; e += 8) {        // 8 edges: 4 per half, 4 loads/lane in flight
        int sA = csr_src[e + 0 + half];
        int sB = csr_src[e + 2 + half];
        int sC = csr_src[e + 4 + half];
        int sD = csr_src[e + 6 + half];
        uint2 vA = Tv[(size_t)sA * 32 + sl];
        uint2 vB = Tv[(size_t)sB * 32 + sl];
        uint2 vC = Tv[(size_t)sC * 32 + sl];
        uint2 vD = Tv[(size_t)sD * 32 + sl];
        a0 += us2f(vA.x & 0xffffu); a1 += hi2f(vA.x); a2 += us2f(vA.y & 0xffffu); a3 += hi2f(vA.y);
        a0 += us2f(vB.x & 0xffffu); a1 += hi2f(vB.x); a2 += us2f(vB.y & 0xffffu); a3 += hi2f(vB.y);
        a0 += us2f(vC.x & 0xffffu); a1 += hi2f(vC.x); a2 += us2f(vC.y & 0xffffu); a3 += hi2f(vC.y);
        a0 += us2f(vD.x & 0xffffu); a1 += hi2f(vD.x); a2 += us2f(vD.y & 0xffffu); a3 += hi2f(vD.y);
    }
    for (; e + 2 <= end; e += 2) {
        int s = csr_src[e + half];
        uint2 v = Tv[(size_t)s * 32 + sl];
        a0 += us2f(v.x & 0xffffu); a1 += hi2f(v.x); a2 += us2f(v.y & 0xffffu); a3 += hi2f(v.y);
    }
    if (e < end && half == 0) {           // odd leftover edge
        int s = csr_src[e];
        uint2 v = Tv[(size_t)s * 32 + sl];
        a0 += us2f(v.x & 0xffffu); a1 += hi2f(v.x); a2 += us2f(v.y & 0xffffu); a3 += hi2f(v.y);
    }
    if (half == 0) {                      // self-loop
        uint2 v = Tv[(size_t)n * 32 + sl];
        a0 += us2f(v.x & 0xffffu); a1 += hi2f(v.x); a2 += us2f(v.y & 0xffffu); a3 += hi2f(v.y);
    }
    a0 += __shfl_xor(a0, 32); a1 += __shfl_xor(a1, 32);
    a2 += __shfl_xor(a2, 32); a3 += __shfl_xor(a3, 32);
    if (half == 0) {
        const float dv = dinv[n];
        uint2 o;
        o.x = pack2(a0 * dv, a1 * dv);
        o.y = pack2(a2 * dv, a3 * dv);
        ((uint2*)O)[(size_t)n * 32 + sl] = o;
    }
}

// ---------------- dual CSR aggregation: one 512B contiguous load covers both rows ----------------
__global__ __launch_bounds__(256) void agg_dual2(const unsigned short* __restrict__ TB23,
                                                 const float* __restrict__ dinv,
                                                 const int* __restrict__ csr_src,
                                                 const int* __restrict__ rend,
                                                 unsigned* __restrict__ OA,
                                                 unsigned* __restrict__ OB, int N) {
    const int n = (blockIdx.x * 256 + threadIdx.x) >> 6;
    const int l = threadIdx.x & 63;
    if (n >= N) return;
    const int start = (n == 0) ? 0 : rend[n - 1];
    const int end   = rend[n];
    const uint2* Tv = (const uint2*)TB23;  // node chunk = 64 uint2: slots 0-31 g2, 32-63 g3

    float a0 = 0.f, a1 = 0.f, a2 = 0.f, a3 = 0.f;
    int e = start;
    for (; e + 4 <= end; e += 4) {
        int s0 = csr_src[e + 0], s1 = csr_src[e + 1], s2 = csr_src[e + 2], s3 = csr_src[e + 3];
        uint2 v0 = Tv[(size_t)s0 * 64 + l];
        uint2 v1 = Tv[(size_t)s1 * 64 + l];
        uint2 v2 = Tv[(size_t)s2 * 64 + l];
        uint2 v3 = Tv[(size_t)s3 * 64 + l];
        a0 += us2f(v0.x & 0xffffu); a1 += hi2f(v0.x); a2 += us2f(v0.y & 0xffffu); a3 += hi2f(v0.y);
        a0 += us2f(v1.x & 0xffffu); a1 += hi2f(v1.x); a2 += us2f(v1.y & 0xffffu); a3 += hi2f(v1.y);
        a0 += us2f(v2.x & 0xffffu); a1 += hi2f(v2.x); a2 += us2f(v2.y & 0xffffu); a3 += hi2f(v2.y);
        a0 += us2f(v3.x & 0xffffu); a1 += hi2f(v3.x); a2 += us2f(v3.y & 0xffffu); a3 += hi2f(v3.y);
    }
    for (; e < end; ++e) {
        int s = csr_src[e];
        uint2 v = Tv[(size_t)s * 64 + l];
        a0 += us2f(v.x & 0xffffu); a1 += hi2f(v.x); a2 += us2f(v.y & 0xffffu); a3 += hi2f(v.y);
    }
    {   // self-loop
        uint2 v = Tv[(size_t)n * 64 + l];
        a0 += us2f(v.x & 0xffffu); a1 += hi2f(v.x); a2 += us2f(v.y & 0xffffu); a3 += hi2f(v.y);
    }
    const float dv = dinv[n];
    uint2 o;
    o.x = pack2(a0 * dv, a1 * dv);
    o.y = pack2(a2 * dv, a3 * dv);
    if (l < 32) ((uint2*)OA)[(size_t)n * 32 + l] = o;
    else        ((uint2*)OB)[(size_t)n * 32 + (l - 32)] = o;
}

// ---------------- MFMA GEMM: T = X @ W + b (bf16 in via LDS; out bf16 or f32) ----------------
#define OM_F32 0
#define OM_BF16 1
#define OM_BF16_SR 2
template <int OMODE, int OSTRIDE>
__global__ __launch_bounds__(256) void gemm_mfma(const unsigned short* __restrict__ Xb,
                                                 const unsigned short* __restrict__ WT,  // [n][k] bf16
                                                 const float* __restrict__ bias,
                                                 const float* __restrict__ dinv,
                                                 void* __restrict__ T, int N) {
    __shared__ unsigned short Xs[64 * 128];   // 16 KB
    __shared__ unsigned short Ws[128 * 128];  // 32 KB
    const int tid = threadIdx.x;
    const int nb = blockIdx.x * 64;

    for (int c = tid; c < 2048; c += 256) {
        int n = c >> 4, kc = c & 15;
        ((uint4*)Ws)[(n << 4) | (kc ^ (n & 7))] = ((const uint4*)WT)[c];
    }
    for (int c = tid; c < 1024; c += 256) {
        int nl = c >> 4, kc = c & 15;
        int n = nb + nl;
        uint4 v = make_uint4(0u, 0u, 0u, 0u);
        if (n < N) v = ((const uint4*)(Xb + (size_t)n * HIDF))[kc];
        ((uint4*)Xs)[(nl << 4) | (kc ^ (nl & 7))] = v;
    }
    __syncthreads();

    const int wv   = tid >> 6;
    const int l    = tid & 63;
    const int row  = l & 15;
    const int kgrp = l >> 4;

    bf16x8 afr[4];
    #pragma unroll
    for (int kk = 0; kk < 4; ++kk) {
        int nl = 16 * wv + row;
        int kc = kk * 4 + kgrp;
        afr[kk] = *(const bf16x8*)(Xs + nl * 128 + ((kc ^ (nl & 7)) << 3));
    }

    f32x4 acc[8];
    #pragma unroll
    for (int nt = 0; nt < 8; ++nt) {
        float b = bias[nt * 16 + row];
        acc[nt] = (f32x4){b, b, b, b};
    }

    #pragma unroll
    for (int nt = 0; nt < 8; ++nt) {
        int col = nt * 16 + row;
        #pragma unroll
        for (int kk = 0; kk < 4; ++kk) {
            int kc = kk * 4 + kgrp;
            bf16x8 bfr = *(const bf16x8*)(Ws + col * 128 + ((kc ^ (col & 7)) << 3));
            acc[nt] = __builtin_amdgcn_mfma_f32_16x16x32_bf16(afr[kk], bfr, acc[nt], 0, 0, 0);
        }
    }

    float dv[4];
    if (OMODE == OM_BF16_SR) {
        #pragma unroll
        for (int r = 0; r < 4; ++r) {
            int grow = nb + 16 * wv + kgrp * 4 + r;
            dv[r] = (grow < N) ? dinv[grow] : 0.f;
        }
    }
    #pragma unroll
    for (int nt = 0; nt < 8; ++nt) {
        int gcol = nt * 16 + row;
        #pragma unroll
        for (int r = 0; r < 4; ++r) {
            int grow = nb + 16 * wv + kgrp * 4 + r;
            if (grow < N) {
                float v = acc[nt][r];
                if (OMODE == OM_BF16_SR) v = fmaxf(v, 0.f) * dv[r];
                if (OMODE == OM_F32) {
                    ((float*)T)[(size_t)grow * OSTRIDE + gcol] = v;
                } else {
                    ((unsigned short*)T)[(size_t)grow * OSTRIDE + gcol] = f2us(v);
                }
            }
        }
    }
}

// ---------------- meta: lane owns cols {2l, 2l+1}; vectorized loads ----------------
__global__ __launch_bounds__(256) void meta_kernel(const float* __restrict__ H1,
                                                   const unsigned* __restrict__ H2B,
                                                   const unsigned* __restrict__ H3B,
                                                   const float* __restrict__ Wa,
                                                   const float* __restrict__ ba,
                                                   const float* __restrict__ Wf,
                                                   const float* __restrict__ bfb,
                                                   float* __restrict__ out, int N) {
    __shared__ float WfS[HIDF * OUTF];  // 32 KB
    __shared__ float WaS[HIDF];
    __shared__ float hm[4][HIDF];
    const int tid = threadIdx.x;
    for (int i = tid; i < HIDF * OUTF; i += 256) WfS[i] = Wf[i];
    if (tid < HIDF) WaS[tid] = Wa[tid];
    __syncthreads();
    const float bav = ba[0];
    const int w = tid >> 6;
    const int l = tid & 63;
    const float bfv = bfb[l];
    const int iters = (N + 3) >> 2;

    for (int it = blockIdx.x; it < iters; it += gridDim.x) {
        const int n = it * 4 + w;
        __syncthreads();
        if (n < N) {
            float2   p1 = ((const float2*)(H1 + (size_t)n * HIDF))[l];     // cols 2l,2l+1
            unsigned u2 = H2B[(size_t)n * 64 + l];
            unsigned u3 = H3B[(size_t)n * 64 + l];
            float h1a = fmaxf(p1.x, 0.f),              h1b = fmaxf(p1.y, 0.f);
            float h2a = fmaxf(us2f(u2 & 0xffffu), 0.f), h2b = fmaxf(hi2f(u2), 0.f);
            float h3a = fmaxf(us2f(u3 & 0xffffu), 0.f), h3b = fmaxf(hi2f(u3), 0.f);
            float wa0 = WaS[2 * l], wa1 = WaS[2 * l + 1];
            float s1 = h1a * wa0 + h1b * wa1;
            float s2 = h2a * wa0 + h2b * wa1;
            float s3 = h3a * wa0 + h3b * wa1;
            #pragma unroll
            for (int off = 32; off; off >>= 1) {
                s1 += __shfl_xor(s1, off);
                s2 += __shfl_xor(s2, off);
                s3 += __shfl_xor(s3, off);
            }
            s1 += bav; s2 += bav; s3 += bav;
            float m  = fmaxf(s1, fmaxf(s2, s3));
            float e1 = expf(s1 - m), e2 = expf(s2 - m), e3 = expf(s3 - m);
            float inv = 1.f / (e1 + e2 + e3);
            float w1 = e1 * inv, w2 = e2 * inv, w3 = e3 * inv;
            hm[w][2 * l]     = w1 * h1a + w2 * h2a + w3 * h3a + h1a;
            hm[w][2 * l + 1] = w1 * h1b + w2 * h2b + w3 * h3b + h1b;
        }
        __syncthreads();
        if (n < N) {
            float acc = bfv;
            #pragma unroll
            for (int k = 0; k < HIDF; ++k) acc = fmaf(hm[w][k], WfS[k * OUTF + l], acc);
            out[(size_t)n * OUTF + l] = acc;
        }
    }
}

// ---------------- launch ----------------
extern "C" void kernel_launch(void* const* d_in, const int* in_sizes, int n_in,
                              void* d_out, int out_size, void* d_ws, size_t ws_size,
                              hipStream_t stream) {
    const float* x   = (const float*)d_in[0];
    const int*   ei  = (const int*)d_in[1];
    const float *W1  = (const float*)d_in[2],  *b1  = (const float*)d_in[3];
    const float *W21 = (const float*)d_in[4],  *b21 = (const float*)d_in[5];
    const float *W22 = (const float*)d_in[6],  *b22 = (const float*)d_in[7];
    const float *W31 = (const float*)d_in[8],  *b31 = (const float*)d_in[9];
    const float *W32 = (const float*)d_in[10], *b32 = (const float*)d_in[11];
    const float *W33 = (const float*)d_in[12], *b33 = (const float*)d_in[13];
    const float *Wa  = (const float*)d_in[14], *ba  = (const float*)d_in[15];
    const float *Wf  = (const float*)d_in[16], *bfb = (const float*)d_in[17];

    const int N = in_sizes[0] / HIDF;
    const int E = in_sizes[1] / 2;
    const int NBK = (N + 127) >> BK_SHIFT;

    // workspace: ints | DINV | TB23 (later aliased by H1F f32) | PXB | AGA | AGB | H2B | WTB
    int*      DEGI    = (int*)d_ws;                        // N
    int*      CURSOR  = DEGI + N;                          // N
    int*      CSR_SRC = CURSOR + N;                        // E
    unsigned* EDG     = (unsigned*)(CSR_SRC + E);          // E packed records
    int*      BCUR    = (int*)(EDG + E);                   // NBK*64 (padded)
    int*      BSUM    = BCUR + 1024 * 64;                  // 256
    int*      BOFF    = BSUM + 256;                        // 256
    float*    DINV    = (float*)(BOFF + 256);              // N
    unsigned short* TB23 = (unsigned short*)(DINV + N);    // N*256 bf16 (later: H1F f32 N*128)
    unsigned* PXB  = (unsigned*)(TB23 + (size_t)N * 256);  // N*64 uints (bf16 pairs)
    unsigned* AGA  = PXB + (size_t)N * 64;                 // N*64 uints
    unsigned* AGB  = AGA + (size_t)N * 64;                 // N*64 uints
    unsigned* H2B  = AGB + (size_t)N * 64;                 // N*64 uints
    unsigned short* WTB = (unsigned short*)(H2B + (size_t)N * 64);  // 6*16384 bf16

    const int gN    = (N + 255) / 256;
    const int gE    = (E + 255) / 256;
    const int gCVT  = (N * 32 + 255) / 256;
    const int gAGG  = (N * 64 + 255) / 256;
    const int gGEMM = (N + 63) / 64;
    const int gMETA = 2048;

    // CSR build (bucketed, packed) + weight pre-transpose
    deg_zero<<<gN, 256, 0, stream>>>(DEGI, N);
    deg_count<<<gE, 256, 0, stream>>>(ei, DEGI, E);
    scanA<<<SCAN_B, 256, 0, stream>>>(DEGI, BSUM, N);
    scanB<<<1, 256, 0, stream>>>(BSUM, BOFF);
    scanC<<<SCAN_B, 256, 0, stream>>>(DEGI, BOFF, CURSOR, DINV, N);
    bcur_init<<<(NBK + 255) / 256, 256, 0, stream>>>(CURSOR, BCUR, N, NBK);
    bucket_scatter<<<gE, 256, 0, stream>>>(ei, BCUR, EDG, E);
    final_scatter_b<<<NBK, 256, 0, stream>>>(EDG, BCUR, CURSOR, CSR_SRC);
    cvt_w<<<384, 256, 0, stream>>>(W21, W31, W22, W32, W33, W1, WTB);

    unsigned short* TBX = TB23;   // plain [n][128] bf16 view of TB23 region

    // TBX = bf16(x*dinv); PXB = bf16( P x )
    cvt_scale<<<gCVT, 256, 0, stream>>>(x, DINV, TBX, N);
    agg_b2<<<gAGG, 256, 0, stream>>>(TBX, DINV, CSR_SRC, CURSOR, PXB, N);

    // branch layer-1: TB23 = {g2, g3}
    gemm_mfma<OM_BF16_SR, 256><<<gGEMM, 256, 0, stream>>>((unsigned short*)PXB, WTB,         b21, DINV, TB23,       N);
    gemm_mfma<OM_BF16_SR, 256><<<gGEMM, 256, 0, stream>>>((unsigned short*)PXB, WTB + 16384, b31, DINV, TB23 + 128, N);
    // fused aggregation: AGA = P g2, AGB = P g3
    agg_dual2<<<gAGG, 256, 0, stream>>>(TB23, DINV, CSR_SRC, CURSOR, AGA, AGB, N);

    // h2 finish: H2B = AGA@W22+b22
    gemm_mfma<OM_BF16, 128><<<gGEMM, 256, 0, stream>>>((unsigned short*)AGA, WTB + 2 * 16384, b22, DINV, H2B, N);
    // h3 second layer: TBX = relu(AGB@W32+b32)*dinv
    gemm_mfma<OM_BF16_SR, 128><<<gGEMM, 256, 0, stream>>>((unsigned short*)AGB, WTB + 3 * 16384, b32, DINV, TBX, N);
    // h3 aggregation: AGA = P TBX
    agg_b2<<<gAGG, 256, 0, stream>>>(TBX, DINV, CSR_SRC, CURSOR, AGA, N);
    // h3 finish: H3B (=AGB) = AGA@W33+b33
    gemm_mfma<OM_BF16, 128><<<gGEMM, 256, 0, stream>>>((unsigned short*)AGA, WTB + 4 * 16384, b33, DINV, AGB, N);

    // h1: H1F (f32, aliases TB23 region; TBX dead) = PXB@W1+b1
    float* H1F = (float*)TB23;
    gemm_mfma<OM_F32, 128><<<gGEMM, 256, 0, stream>>>((unsigned short*)PXB, WTB + 5 * 16384, b1, DINV, H1F, N);

    // meta combine + final projection
    meta_kernel<<<gMETA, 256, 0, stream>>>(H1F, H2B, AGB, Wa, ba, Wf, bfb,
                                           (float*)d_out, N);
}